// Round 2
// baseline (2259.106 us; speedup 1.0000x reference)
//
#include <hip/hip_runtime.h>
#include <hip/hip_bf16.h>
#include <math.h>

#define S 1024
#define B 4
#define Dm 768
#define NH 12
#define DH 64
#define NL 4
#define DI 3072
#define QS 2304   // row stride of fused qkv activation buffer
#define MU_CHUNK 16  // S-dim split for memupd

typedef __hip_bfloat16 bf16;
typedef short bf16x8 __attribute__((ext_vector_type(8)));
typedef float f32x4 __attribute__((ext_vector_type(4)));

__device__ __forceinline__ float b2f(bf16 x) { return __bfloat162float(x); }
__device__ __forceinline__ bf16 f2b(float x) { return __float2bfloat16(x); }

__device__ __forceinline__ float ldv(const float* p, size_t i) { return p[i]; }
__device__ __forceinline__ float ldv(const bf16* p, size_t i) { return b2f(p[i]); }

__device__ __forceinline__ float wave_sum(float x) {
  #pragma unroll
  for (int off = 32; off > 0; off >>= 1) x += __shfl_xor(x, off, 64);
  return x;
}

// async 16B global -> LDS DMA. LDS dest = wave-uniform base + lane*16.
typedef const __attribute__((address_space(1))) unsigned int guint;
typedef __attribute__((address_space(3))) unsigned int luint;
__device__ __forceinline__ void async_cp16(const void* g, void* l) {
  __builtin_amdgcn_global_load_lds((guint*)g, (luint*)l, 16, 0, 0);
}

// h[s,b,d] = word_emb[inp[s,b], d] * sqrt(D) + pos_emb(s, d); fp32 + bf16 copies
__global__ void embed_kernel(const int* __restrict__ inp, const float* __restrict__ wemb,
                             float* __restrict__ h, bf16* __restrict__ hb) {
  int idx = blockIdx.x * blockDim.x + threadIdx.x;
  if (idx >= S * B * Dm) return;
  int d = idx % Dm;
  int sb = idx / Dm;
  int b = sb % B;
  int s = sb / B;
  int tok = inp[s * B + b];
  float e = wemb[(size_t)tok * Dm + d] * 27.712812921102035f; // sqrt(768)
  float ps = (float)(S - 1 - s);
  float pe;
  if (d < Dm / 2) {
    float invf = expf(-(2.0f * (float)d / (float)Dm) * 9.210340371976184f); // ln(10000)
    pe = sinf(ps * invf);
  } else {
    int j = d - Dm / 2;
    float invf = expf(-(2.0f * (float)j / (float)Dm) * 9.210340371976184f);
    pe = cosf(ps * invf);
  }
  float val = e + pe;
  h[idx] = val;
  hb[idx] = f2b(val);
}

// pack one layer's weights to bf16 into wb:
//   [qkv 2304x768 | wo 768x768 | w1 3072x768 | w2 768x3072]  (all B^T, K contiguous)
#define SEG_QKV 1769472
#define SEG_WO  2359296
#define SEG_W1  4718592
#define SEG_END 7077888
__global__ void convw_kernel(const float* __restrict__ Wq, const float* __restrict__ Wkv,
                             const float* __restrict__ Wo, const float* __restrict__ W1,
                             const float* __restrict__ W2, bf16* __restrict__ dst) {
  int idx = (blockIdx.x * blockDim.x + threadIdx.x) * 4;
  if (idx >= SEG_END) return;
  const float* src;
  if (idx < SEG_QKV) {
    src = (idx < 589824) ? Wq + idx : Wkv + (idx - 589824);
  } else if (idx < SEG_WO) {
    src = Wo + (idx - SEG_QKV);
  } else if (idx < SEG_W1) {
    src = W1 + (idx - SEG_WO);
  } else {
    src = W2 + (idx - SEG_W1);
  }
  float4 f = *(const float4*)src;
  bf16 b0 = f2b(f.x), b1 = f2b(f.y), b2 = f2b(f.z), b3 = f2b(f.w);
  unsigned short o[4];
  o[0] = *(unsigned short*)&b0; o[1] = *(unsigned short*)&b1;
  o[2] = *(unsigned short*)&b2; o[3] = *(unsigned short*)&b3;
  *(uint2*)((unsigned short*)dst + idx) = *(uint2*)o;
}

// C[M,N] = A[M,K] @ W[N,K]^T (+bias)(+relu). bf16 in, fp32 acc, bf16 out.
// 256 thr = 4 waves (2x2). BN=128, BM=32*MREP (128 or 64), BK=32.
// LDS layout = MFMA-fragment order: 16-row tile T (1KB) holds elem (m,k) at
// T*512 + (k>>3)*128 + (m&15)*8 + (k&7). global_load_lds writes linearly
// (lane*16B), so the per-lane GLOBAL source is pre-swizzled to match:
//   issue i, wave w, lane l  ->  row = i*64 + w*16 + (l&15), k = (l>>4)*8.
template <int MREP, int RELU>
__global__ __launch_bounds__(256) void gemm_async(const bf16* __restrict__ A,
                                                  const bf16* __restrict__ W,
                                                  const float* __restrict__ bias,
                                                  bf16* __restrict__ C,
                                                  int ldc, int K) {
  constexpr int BM = MREP * 32;
  __shared__ __align__(16) unsigned short Asm[BM * 32];
  __shared__ __align__(16) unsigned short Bsm[128 * 32];
  const int t = threadIdx.x;
  const int w = t >> 6, lane = t & 63;
  const int col = lane & 15, quad = lane >> 4;
  const int wm = w >> 1, wn = w & 1;
  const int m0 = blockIdx.y * BM, n0 = blockIdx.x * 128;

  const bf16* aSrc = A + (size_t)(m0 + w * 16 + col) * K + quad * 8;
  const bf16* bSrc = W + (size_t)(n0 + w * 16 + col) * K + quad * 8;

  const f32x4 zf = {0.0f, 0.0f, 0.0f, 0.0f};
  f32x4 acc[MREP][4];
  #pragma unroll
  for (int mt = 0; mt < MREP; mt++)
    #pragma unroll
    for (int nt = 0; nt < 4; nt++) acc[mt][nt] = zf;

  for (int kk = 0; kk < K; kk += 32) {
    __syncthreads();                 // prior iteration's frag reads complete
    #pragma unroll
    for (int i = 0; i < MREP / 2; i++)
      async_cp16(aSrc + kk + (size_t)i * 64 * K, &Asm[i * 2048 + w * 512]);
    #pragma unroll
    for (int i = 0; i < 2; i++)
      async_cp16(bSrc + kk + (size_t)i * 64 * K, &Bsm[i * 2048 + w * 512]);
    __syncthreads();                 // compiler drains vmcnt(0) before barrier
    bf16x8 af[MREP], bfr[4];
    #pragma unroll
    for (int mt = 0; mt < MREP; mt++)
      af[mt] = *(const bf16x8*)&Asm[(wm * MREP + mt) * 512 + lane * 8];
    #pragma unroll
    for (int nt = 0; nt < 4; nt++)
      bfr[nt] = *(const bf16x8*)&Bsm[(wn * 4 + nt) * 512 + lane * 8];
    #pragma unroll
    for (int mt = 0; mt < MREP; mt++)
      #pragma unroll
      for (int nt = 0; nt < 4; nt++)
        acc[mt][nt] = __builtin_amdgcn_mfma_f32_16x16x32_bf16(af[mt], bfr[nt],
                                                              acc[mt][nt], 0, 0, 0);
  }

  #pragma unroll
  for (int nt = 0; nt < 4; nt++) {
    const int colg = n0 + wn * 64 + nt * 16 + col;
    const float bv = bias ? bias[colg] : 0.0f;
    #pragma unroll
    for (int mt = 0; mt < MREP; mt++) {
      #pragma unroll
      for (int r = 0; r < 4; r++) {
        const int row = m0 + wm * (MREP * 16) + mt * 16 + quad * 4 + r;
        float val = acc[mt][nt][r] + bv;
        if (RELU) val = fmaxf(val, 0.0f);
        C[(size_t)row * ldc + colg] = f2b(val);
      }
    }
  }
}

// Flash attention with MFMA. Block = 256 thr = 4 waves; one 64-row Q tile per (b,n).
// q/k/v read from fused qkv buffer (row stride QS); att written with stride Dm.
__global__ __launch_bounds__(256) void attn_flash(const bf16* __restrict__ q,
                                                  const bf16* __restrict__ k,
                                                  const bf16* __restrict__ v,
                                                  bf16* __restrict__ att) {
  const int it = blockIdx.x;       // q-tile index (16)
  const int bn = blockIdx.y;       // b*NH+n (48)
  const int b = bn / NH, n = bn % NH;
  const int t = threadIdx.x;
  const int w = t >> 6, lane = t & 63;
  const int col = lane & 15, quad = lane >> 4;
  const int i0 = it * 64;

  __shared__ __align__(16) unsigned short Kt[64 * 72];  // K[j][d], row stride 72
  __shared__ __align__(16) unsigned short Vt[64 * 72];  // V^T[d][j]
  __shared__ __align__(16) unsigned short Pw[64 * 72];  // per-wave P rows

  const unsigned short* qp = (const unsigned short*)q;
  const unsigned short* kp = (const unsigned short*)k;
  const unsigned short* vp = (const unsigned short*)v;

  bf16x8 aq[2];
  {
    size_t qb = ((size_t)(i0 + w * 16 + col) * B + b) * QS + n * DH + quad * 8;
    aq[0] = *(const bf16x8*)(qp + qb);
    aq[1] = *(const bf16x8*)(qp + qb + 32);
  }

  const f32x4 zf = {0.0f, 0.0f, 0.0f, 0.0f};
  float mrow[4], lrow[4];
  f32x4 o[4];
  #pragma unroll
  for (int r = 0; r < 4; r++) { mrow[r] = -1e30f; lrow[r] = 0.0f; }
  #pragma unroll
  for (int db = 0; db < 4; db++) o[db] = zf;

  const int jj = t >> 2;           // 0..63 (staging row)
  const int d0 = (t & 3) << 4;     // 0,16,32,48

  for (int jt = 0; jt <= it; jt++) {
    const int j0 = jt * 64;
    __syncthreads();
    {
      size_t gb = ((size_t)(j0 + jj) * B + b) * QS + n * DH + d0;
      *(uint4*)&Kt[jj * 72 + d0] = *(const uint4*)(kp + gb);
      *(uint4*)&Kt[jj * 72 + d0 + 8] = *(const uint4*)(kp + gb + 8);
      unsigned short tv[16];
      *(uint4*)tv = *(const uint4*)(vp + gb);
      *(uint4*)(tv + 8) = *(const uint4*)(vp + gb + 8);
      #pragma unroll
      for (int x = 0; x < 16; x++) Vt[(d0 + x) * 72 + jj] = tv[x];
    }
    __syncthreads();

    f32x4 sf[4];
    #pragma unroll
    for (int nb = 0; nb < 4; nb++) sf[nb] = zf;
    #pragma unroll
    for (int ks = 0; ks < 2; ks++) {
      #pragma unroll
      for (int nb = 0; nb < 4; nb++) {
        bf16x8 kb = *(const bf16x8*)&Kt[(nb * 16 + col) * 72 + ks * 32 + quad * 8];
        sf[nb] = __builtin_amdgcn_mfma_f32_16x16x32_bf16(aq[ks], kb, sf[nb], 0, 0, 0);
      }
    }

    const bool diag = (jt == it);
    #pragma unroll
    for (int r = 0; r < 4; r++) {
      const int irow = i0 + w * 16 + quad * 4 + r;
      float sv[4];
      #pragma unroll
      for (int nb = 0; nb < 4; nb++) {
        float s = sf[nb][r] * 0.125f;
        if (diag && (j0 + nb * 16 + col) > irow) s = -1e30f;
        sv[nb] = s;
      }
      float rm = fmaxf(fmaxf(sv[0], sv[1]), fmaxf(sv[2], sv[3]));
      #pragma unroll
      for (int off = 8; off > 0; off >>= 1) rm = fmaxf(rm, __shfl_xor(rm, off, 64));
      const float mn = fmaxf(mrow[r], rm);
      const float alpha = __expf(mrow[r] - mn);
      mrow[r] = mn;
      float ps = 0.0f;
      #pragma unroll
      for (int nb = 0; nb < 4; nb++) {
        float p = __expf(sv[nb] - mn);
        ps += p;
        bf16 hb = f2b(p);
        Pw[(w * 16 + quad * 4 + r) * 72 + nb * 16 + col] = *(unsigned short*)&hb;
      }
      #pragma unroll
      for (int off = 8; off > 0; off >>= 1) ps += __shfl_xor(ps, off, 64);
      lrow[r] = lrow[r] * alpha + ps;
      #pragma unroll
      for (int db = 0; db < 4; db++) o[db][r] *= alpha;
    }

    #pragma unroll
    for (int ks = 0; ks < 2; ks++) {
      bf16x8 pa = *(const bf16x8*)&Pw[(w * 16 + col) * 72 + ks * 32 + quad * 8];
      #pragma unroll
      for (int db = 0; db < 4; db++) {
        bf16x8 vb = *(const bf16x8*)&Vt[(db * 16 + col) * 72 + ks * 32 + quad * 8];
        o[db] = __builtin_amdgcn_mfma_f32_16x16x32_bf16(pa, vb, o[db], 0, 0, 0);
      }
    }
  }

  unsigned short* ap = (unsigned short*)att;
  #pragma unroll
  for (int r = 0; r < 4; r++) {
    const int irow = i0 + w * 16 + quad * 4 + r;
    const float inv = 1.0f / lrow[r];
    size_t ob = ((size_t)irow * B + b) * Dm + n * DH + col;
    #pragma unroll
    for (int db = 0; db < 4; db++) {
      bf16 hb = f2b(o[db][r] * inv);
      ap[ob + db * 16] = *(unsigned short*)&hb;
    }
  }
}

// content retrieval + gated combine, and vd = k - delta (uses cK = elu(v)+1 !)
// q/k/v at qkv stride QS (offsets 0/768/1536); att/vd stride Dm.
__global__ void meminfer_kernel(const bf16* __restrict__ qkv,
                                const float* __restrict__ mem, const float* __restrict__ mnorm,
                                bf16* __restrict__ att, bf16* __restrict__ vd) {
  int wid = threadIdx.x >> 6;
  int lane = threadIdx.x & 63;
  int row = blockIdx.x * 4 + wid;      // ((s*B)+b)*NH+n
  int n = row % NH;
  int sb = row / NH;
  int baseq = sb * QS + n * DH;
  int based = sb * Dm + n * DH;
  int b = sb % B;
  float qv = b2f(qkv[baseq + lane]);
  float kv = b2f(qkv[baseq + 768 + lane]);
  float vv = b2f(qkv[baseq + 1536 + lane]);
  float cq = qv > 0.0f ? qv + 1.0f : expf(qv);   // elu+1
  float ck = vv > 0.0f ? vv + 1.0f : expf(vv);
  float nr = mnorm[(size_t)(b * NH + n) * DH + lane];
  float denq = wave_sum(cq * nr);
  float denk = wave_sum(ck * nr);
  const float* mrow = mem + (size_t)(b * NH + n) * DH * DH;
  float numq = 0.0f, numk = 0.0f;
  #pragma unroll 8
  for (int kk = 0; kk < DH; kk++) {
    float mval = mrow[(size_t)kk * DH + lane];
    numq += __shfl(cq, kk, 64) * mval;
    numk += __shfl(ck, kk, 64) * mval;
  }
  float gate = 1.0f / (1.0f + expf(-0.01f));
  float content = numq / denq;
  float delta = numk / denk;
  att[based + lane] = f2b(gate * content + (1.0f - gate) * b2f(att[based + lane]));
  vd[based + lane] = f2b(kv - delta);
}

// out_mem = mem; out_norm = mnorm  (fp32 copy so memupd can be purely additive)
__global__ void meminit_kernel(const float* __restrict__ mem, const float* __restrict__ mnorm,
                               float* __restrict__ out_mem, float* __restrict__ out_norm) {
  int i4 = (blockIdx.x * blockDim.x + threadIdx.x) * 4;
  const int MEMN = B * NH * DH * DH;   // 786432
  if (i4 < MEMN) {
    *(float4*)(out_mem + i4) = *(const float4*)(mem + i4);
  } else {
    int j = i4 - MEMN;
    if (j < B * NH * DH) *(float4*)(out_norm + j) = *(const float4*)(mnorm + j);
  }
}

// out_mem[b,n,k,v] += sum_{s in chunk} cK[s,k]*vd[s,v];  out_norm[b,n,k] += sum cK[s,k]
// grid = B*NH*MU_CHUNK blocks; chunk c covers s in [c*64, c*64+64). Atomic accumulate
// (out pre-initialized with mem by meminit_kernel; fp32 reassociation noise ~1e-7 rel).
__global__ void memupd_kernel(const bf16* __restrict__ qkv, const bf16* __restrict__ vd,
                              float* __restrict__ out_mem, float* __restrict__ out_norm) {
  int bn = blockIdx.x % (B * NH);
  int c = blockIdx.x / (B * NH);
  int b = bn / NH, n = bn % NH;
  int t = threadIdx.x;        // 256
  int k = t >> 2;             // 0..63
  int v0 = (t & 3) * 16;      // 0,16,32,48
  __shared__ float ckl[8][DH];
  __shared__ float vdl[8][DH];
  float acc[16];
  #pragma unroll
  for (int j = 0; j < 16; j++) acc[j] = 0.0f;
  float nsum = 0.0f;
  const int sBeg = c * (S / MU_CHUNK), sEnd = sBeg + S / MU_CHUNK;
  for (int s0 = sBeg; s0 < sEnd; s0 += 8) {
    #pragma unroll
    for (int i2 = 0; i2 < 2; i2++) {
      int idx = t + i2 * 256;        // 0..511
      int sp = idx >> 6, dd = idx & 63;
      int gq = ((s0 + sp) * B + b) * QS + 1536 + n * DH + dd;   // v
      int gd = ((s0 + sp) * B + b) * Dm + n * DH + dd;          // vd
      float vv = b2f(qkv[gq]);
      ckl[sp][dd] = vv > 0.0f ? vv + 1.0f : expf(vv);
      vdl[sp][dd] = b2f(vd[gd]);
    }
    __syncthreads();
    #pragma unroll
    for (int sp = 0; sp < 8; sp++) {
      float cc = ckl[sp][k];
      if ((t & 3) == 0) nsum += cc;
      #pragma unroll
      for (int j = 0; j < 16; j++) acc[j] += cc * vdl[sp][v0 + j];
    }
    __syncthreads();
  }
  float* orow = out_mem + (size_t)(b * NH + n) * DH * DH;
  #pragma unroll
  for (int j = 0; j < 16; j++) {
    atomicAdd(&orow[k * DH + v0 + j], acc[j]);
  }
  if ((t & 3) == 0) {
    atomicAdd(&out_norm[(b * NH + n) * DH + k], nsum);
  }
}

// out = layer_norm(x + y, g, b); one block per row of 768. fp32 and/or bf16 out.
template <typename TX, typename TY>
__global__ void addln_kernel(const TX* __restrict__ x, const TY* __restrict__ y,
                             const float* __restrict__ g, const float* __restrict__ bb,
                             float* __restrict__ outf, bf16* __restrict__ outb) {
  int row = blockIdx.x;
  int t = threadIdx.x;      // 256
  float vals[3];
  float sum = 0.0f, sq = 0.0f;
  #pragma unroll
  for (int i = 0; i < 3; i++) {
    size_t idx = (size_t)row * Dm + t + i * 256;
    float vv = ldv(x, idx) + ldv(y, idx);
    vals[i] = vv;
    sum += vv;
    sq += vv * vv;
  }
  sum = wave_sum(sum);
  sq = wave_sum(sq);
  __shared__ float s1[4], s2[4];
  int w = t >> 6, lane = t & 63;
  if (lane == 0) { s1[w] = sum; s2[w] = sq; }
  __syncthreads();
  if (t == 0) {
    s1[0] = s1[0] + s1[1] + s1[2] + s1[3];
    s2[0] = s2[0] + s2[1] + s2[2] + s2[3];
  }
  __syncthreads();
  sum = s1[0]; sq = s2[0];
  float mu = sum / 768.0f;
  float var = sq / 768.0f - mu * mu;
  float rs = rsqrtf(var + 1e-5f);
  #pragma unroll
  for (int i = 0; i < 3; i++) {
    int d = t + i * 256;
    float o = (vals[i] - mu) * rs * g[d] + bb[d];
    size_t idx = (size_t)row * Dm + d;
    if (outf) outf[idx] = o;
    if (outb) outb[idx] = f2b(o);
  }
}

extern "C" void kernel_launch(void* const* d_in, const int* in_sizes, int n_in,
                              void* d_out, int out_size, void* d_ws, size_t ws_size,
                              hipStream_t stream) {
  (void)in_sizes; (void)n_in; (void)out_size; (void)ws_size;
  const int*   inp   = (const int*)d_in[0];
  const float* wemb  = (const float*)d_in[1];
  const float* Wq    = (const float*)d_in[2];
  const float* Wkv   = (const float*)d_in[3];
  const float* Wo    = (const float*)d_in[4];
  const float* ln1g  = (const float*)d_in[5];
  const float* ln1b  = (const float*)d_in[6];
  const float* fW1   = (const float*)d_in[7];
  const float* fb1   = (const float*)d_in[8];
  const float* fW2   = (const float*)d_in[9];
  const float* fb2   = (const float*)d_in[10];
  const float* ln2g  = (const float*)d_in[11];
  const float* ln2b  = (const float*)d_in[12];
  const float* mem   = (const float*)d_in[13];
  const float* mnorm = (const float*)d_in[14];

  const size_t SBD = (size_t)S * B * Dm;   // 3,145,728

  bf16* ws   = (bf16*)d_ws;
  bf16* qkv  = ws;              // slots 0-2: fused qkv, [4096][2304]
  bf16* vd   = ws + 3 * SBD;    // slot 3
  bf16* att  = ws + 4 * SBD;    // slot 4 (aliased: h_bf, ff2o — all disjoint in time)
  bf16* hbf  = att;
  bf16* ff2o = att;
  bf16* out1 = ws + 5 * SBD;    // slot 5
  bf16* wb   = ws + 6 * SBD;    // bf16 weight pack for current layer (7,077,888 elems)
  bf16* ffm  = ws;              // 4*SBD: aliases slots 0-3 (dead by FF1)
  bf16* tmp  = ws;              // Wo-GEMM out (qkv dead after memupd)

  float* h    = (float*)d_out;  // residual stream lives in d_out (fp32)
  float* outm = h + SBD;
  float* outn = outm + (size_t)NL * B * NH * DH * DH;

  dim3 b256(256);
  embed_kernel<<<dim3((S * B * Dm + 255) / 256), b256, 0, stream>>>(inp, wemb, h, hbf);

  for (int l = 0; l < NL; l++) {
    convw_kernel<<<dim3(SEG_END / 4 / 256), b256, 0, stream>>>(
        Wq + (size_t)l * Dm * Dm, Wkv + (size_t)l * 2 * Dm * Dm,
        Wo + (size_t)l * Dm * Dm, fW1 + (size_t)l * DI * Dm,
        fW2 + (size_t)l * Dm * DI, wb);
    const bf16* wqkv = wb;
    const bf16* wo_b = wb + SEG_QKV;
    const bf16* w1_b = wb + SEG_WO;
    const bf16* w2_b = wb + SEG_W1;
    const float* mem_l = mem + (size_t)l * B * NH * DH * DH;
    const float* mn_l  = mnorm + (size_t)l * B * NH * DH;
    float* outm_l = outm + (size_t)l * B * NH * DH * DH;
    float* outn_l = outn + (size_t)l * B * NH * DH;

    // fused QKV: M=4096, N=2304, K=768 -> 576 blocks
    gemm_async<4, 0><<<dim3(QS / 128, 32), b256, 0, stream>>>(hbf, wqkv, nullptr, qkv, QS, Dm);

    attn_flash<<<dim3(S / 64, B * NH), b256, 0, stream>>>(qkv, qkv + 768, qkv + 1536, att);
    meminfer_kernel<<<dim3(S * B * NH / 4), b256, 0, stream>>>(qkv, mem_l, mn_l, att, vd);
    meminit_kernel<<<dim3((B * NH * DH * DH + B * NH * DH) / 1024), b256, 0, stream>>>(
        mem_l, mn_l, outm_l, outn_l);
    memupd_kernel<<<dim3(B * NH * MU_CHUNK), b256, 0, stream>>>(qkv, vd, outm_l, outn_l);

    // Wo: N=768 -> BM=64 tile, 384 blocks
    gemm_async<2, 0><<<dim3(Dm / 128, 64), b256, 0, stream>>>(att, wo_b, nullptr, tmp, Dm, Dm);
    addln_kernel<float, bf16><<<dim3(S * B), b256, 0, stream>>>(
        h, tmp, ln1g + l * Dm, ln1b + l * Dm, nullptr, out1);

    // FF1: M=4096, N=3072, K=768 -> 768 blocks
    gemm_async<4, 1><<<dim3(DI / 128, 32), b256, 0, stream>>>(out1, w1_b, fb1 + (size_t)l * DI,
                                                              ffm, DI, Dm);
    // FF2: N=768, K=3072 -> BM=64 tile, 384 blocks
    gemm_async<2, 0><<<dim3(Dm / 128, 64), b256, 0, stream>>>(ffm, w2_b, fb2 + (size_t)l * Dm,
                                                              ff2o, Dm, DI);
    addln_kernel<bf16, bf16><<<dim3(S * B), b256, 0, stream>>>(
        out1, ff2o, ln2g + l * Dm, ln2b + l * Dm, h, hbf);
  }
}

// Round 3
// 1615.993 us; speedup vs baseline: 1.3980x; 1.3980x over previous
//
#include <hip/hip_runtime.h>
#include <hip/hip_bf16.h>
#include <math.h>

#define S 1024
#define B 4
#define Dm 768
#define NH 12
#define DH 64
#define NL 4
#define DI 3072
#define QS 2304   // row stride of fused qkv activation buffer
#define MU_CHUNK 8   // S-dim split for memupd (partials fit exactly in out1 slot)

typedef __hip_bfloat16 bf16;
typedef short bf16x8 __attribute__((ext_vector_type(8)));
typedef float f32x4 __attribute__((ext_vector_type(4)));

__device__ __forceinline__ float b2f(bf16 x) { return __bfloat162float(x); }
__device__ __forceinline__ bf16 f2b(float x) { return __float2bfloat16(x); }

__device__ __forceinline__ float ldv(const float* p, size_t i) { return p[i]; }
__device__ __forceinline__ float ldv(const bf16* p, size_t i) { return b2f(p[i]); }

__device__ __forceinline__ float wave_sum(float x) {
  #pragma unroll
  for (int off = 32; off > 0; off >>= 1) x += __shfl_xor(x, off, 64);
  return x;
}

// async 16B global -> LDS DMA. LDS dest = wave-uniform base + lane*16.
typedef const __attribute__((address_space(1))) unsigned int guint;
typedef __attribute__((address_space(3))) unsigned int luint;
__device__ __forceinline__ void async_cp16(const void* g, void* l) {
  __builtin_amdgcn_global_load_lds((guint*)g, (luint*)l, 16, 0, 0);
}

// h[s,b,d] = word_emb[inp[s,b], d] * sqrt(D) + pos_emb(s, d); fp32 + bf16 copies
__global__ void embed_kernel(const int* __restrict__ inp, const float* __restrict__ wemb,
                             float* __restrict__ h, bf16* __restrict__ hb) {
  int idx = blockIdx.x * blockDim.x + threadIdx.x;
  if (idx >= S * B * Dm) return;
  int d = idx % Dm;
  int sb = idx / Dm;
  int b = sb % B;
  int s = sb / B;
  int tok = inp[s * B + b];
  float e = wemb[(size_t)tok * Dm + d] * 27.712812921102035f; // sqrt(768)
  float ps = (float)(S - 1 - s);
  float pe;
  if (d < Dm / 2) {
    float invf = expf(-(2.0f * (float)d / (float)Dm) * 9.210340371976184f); // ln(10000)
    pe = sinf(ps * invf);
  } else {
    int j = d - Dm / 2;
    float invf = expf(-(2.0f * (float)j / (float)Dm) * 9.210340371976184f);
    pe = cosf(ps * invf);
  }
  float val = e + pe;
  h[idx] = val;
  hb[idx] = f2b(val);
}

// pack one layer's weights to bf16 into wb:
//   [qkv 2304x768 | wo 768x768 | w1 3072x768 | w2 768x3072]  (all B^T, K contiguous)
#define SEG_QKV 1769472
#define SEG_WO  2359296
#define SEG_W1  4718592
#define SEG_END 7077888
__global__ void convw_kernel(const float* __restrict__ Wq, const float* __restrict__ Wkv,
                             const float* __restrict__ Wo, const float* __restrict__ W1,
                             const float* __restrict__ W2, bf16* __restrict__ dst) {
  int idx = (blockIdx.x * blockDim.x + threadIdx.x) * 4;
  if (idx >= SEG_END) return;
  const float* src;
  if (idx < SEG_QKV) {
    src = (idx < 589824) ? Wq + idx : Wkv + (idx - 589824);
  } else if (idx < SEG_WO) {
    src = Wo + (idx - SEG_QKV);
  } else if (idx < SEG_W1) {
    src = W1 + (idx - SEG_WO);
  } else {
    src = W2 + (idx - SEG_W1);
  }
  float4 f = *(const float4*)src;
  bf16 b0 = f2b(f.x), b1 = f2b(f.y), b2 = f2b(f.z), b3 = f2b(f.w);
  unsigned short o[4];
  o[0] = *(unsigned short*)&b0; o[1] = *(unsigned short*)&b1;
  o[2] = *(unsigned short*)&b2; o[3] = *(unsigned short*)&b3;
  *(uint2*)((unsigned short*)dst + idx) = *(uint2*)o;
}

// C[M,N] = A[M,K] @ W[N,K]^T (+bias)(+relu). bf16 in, fp32 acc, bf16 out.
// 256 thr = 4 waves (2x2). BN=128, BM=32*MREP (128 or 64), BK=32.
// LDS layout = MFMA-fragment order: 16-row tile T (1KB) holds elem (m,k) at
// T*512 + (k>>3)*128 + (m&15)*8 + (k&7). global_load_lds writes linearly
// (lane*16B), so the per-lane GLOBAL source is pre-swizzled to match:
//   issue i, wave w, lane l  ->  row = i*64 + w*16 + (l&15), k = (l>>4)*8.
template <int MREP, int RELU>
__global__ __launch_bounds__(256) void gemm_async(const bf16* __restrict__ A,
                                                  const bf16* __restrict__ W,
                                                  const float* __restrict__ bias,
                                                  bf16* __restrict__ C,
                                                  int ldc, int K) {
  constexpr int BM = MREP * 32;
  __shared__ __align__(16) unsigned short Asm[BM * 32];
  __shared__ __align__(16) unsigned short Bsm[128 * 32];
  const int t = threadIdx.x;
  const int w = t >> 6, lane = t & 63;
  const int col = lane & 15, quad = lane >> 4;
  const int wm = w >> 1, wn = w & 1;
  const int m0 = blockIdx.y * BM, n0 = blockIdx.x * 128;

  const bf16* aSrc = A + (size_t)(m0 + w * 16 + col) * K + quad * 8;
  const bf16* bSrc = W + (size_t)(n0 + w * 16 + col) * K + quad * 8;

  const f32x4 zf = {0.0f, 0.0f, 0.0f, 0.0f};
  f32x4 acc[MREP][4];
  #pragma unroll
  for (int mt = 0; mt < MREP; mt++)
    #pragma unroll
    for (int nt = 0; nt < 4; nt++) acc[mt][nt] = zf;

  for (int kk = 0; kk < K; kk += 32) {
    __syncthreads();                 // prior iteration's frag reads complete
    #pragma unroll
    for (int i = 0; i < MREP / 2; i++)
      async_cp16(aSrc + kk + (size_t)i * 64 * K, &Asm[i * 2048 + w * 512]);
    #pragma unroll
    for (int i = 0; i < 2; i++)
      async_cp16(bSrc + kk + (size_t)i * 64 * K, &Bsm[i * 2048 + w * 512]);
    __syncthreads();                 // compiler drains vmcnt(0) before barrier
    bf16x8 af[MREP], bfr[4];
    #pragma unroll
    for (int mt = 0; mt < MREP; mt++)
      af[mt] = *(const bf16x8*)&Asm[(wm * MREP + mt) * 512 + lane * 8];
    #pragma unroll
    for (int nt = 0; nt < 4; nt++)
      bfr[nt] = *(const bf16x8*)&Bsm[(wn * 4 + nt) * 512 + lane * 8];
    #pragma unroll
    for (int mt = 0; mt < MREP; mt++)
      #pragma unroll
      for (int nt = 0; nt < 4; nt++)
        acc[mt][nt] = __builtin_amdgcn_mfma_f32_16x16x32_bf16(af[mt], bfr[nt],
                                                              acc[mt][nt], 0, 0, 0);
  }

  #pragma unroll
  for (int nt = 0; nt < 4; nt++) {
    const int colg = n0 + wn * 64 + nt * 16 + col;
    const float bv = bias ? bias[colg] : 0.0f;
    #pragma unroll
    for (int mt = 0; mt < MREP; mt++) {
      #pragma unroll
      for (int r = 0; r < 4; r++) {
        const int row = m0 + wm * (MREP * 16) + mt * 16 + quad * 4 + r;
        float val = acc[mt][nt][r] + bv;
        if (RELU) val = fmaxf(val, 0.0f);
        C[(size_t)row * ldc + colg] = f2b(val);
      }
    }
  }
}

// Flash attention with MFMA. Block = 256 thr = 4 waves; one 64-row Q tile per (b,n).
// q/k/v read from fused qkv buffer (row stride QS); att written with stride Dm.
__global__ __launch_bounds__(256) void attn_flash(const bf16* __restrict__ q,
                                                  const bf16* __restrict__ k,
                                                  const bf16* __restrict__ v,
                                                  bf16* __restrict__ att) {
  const int it = blockIdx.x;       // q-tile index (16)
  const int bn = blockIdx.y;       // b*NH+n (48)
  const int b = bn / NH, n = bn % NH;
  const int t = threadIdx.x;
  const int w = t >> 6, lane = t & 63;
  const int col = lane & 15, quad = lane >> 4;
  const int i0 = it * 64;

  __shared__ __align__(16) unsigned short Kt[64 * 72];  // K[j][d], row stride 72
  __shared__ __align__(16) unsigned short Vt[64 * 72];  // V^T[d][j]
  __shared__ __align__(16) unsigned short Pw[64 * 72];  // per-wave P rows

  const unsigned short* qp = (const unsigned short*)q;
  const unsigned short* kp = (const unsigned short*)k;
  const unsigned short* vp = (const unsigned short*)v;

  bf16x8 aq[2];
  {
    size_t qb = ((size_t)(i0 + w * 16 + col) * B + b) * QS + n * DH + quad * 8;
    aq[0] = *(const bf16x8*)(qp + qb);
    aq[1] = *(const bf16x8*)(qp + qb + 32);
  }

  const f32x4 zf = {0.0f, 0.0f, 0.0f, 0.0f};
  float mrow[4], lrow[4];
  f32x4 o[4];
  #pragma unroll
  for (int r = 0; r < 4; r++) { mrow[r] = -1e30f; lrow[r] = 0.0f; }
  #pragma unroll
  for (int db = 0; db < 4; db++) o[db] = zf;

  const int jj = t >> 2;           // 0..63 (staging row)
  const int d0 = (t & 3) << 4;     // 0,16,32,48

  for (int jt = 0; jt <= it; jt++) {
    const int j0 = jt * 64;
    __syncthreads();
    {
      size_t gb = ((size_t)(j0 + jj) * B + b) * QS + n * DH + d0;
      *(uint4*)&Kt[jj * 72 + d0] = *(const uint4*)(kp + gb);
      *(uint4*)&Kt[jj * 72 + d0 + 8] = *(const uint4*)(kp + gb + 8);
      unsigned short tv[16];
      *(uint4*)tv = *(const uint4*)(vp + gb);
      *(uint4*)(tv + 8) = *(const uint4*)(vp + gb + 8);
      #pragma unroll
      for (int x = 0; x < 16; x++) Vt[(d0 + x) * 72 + jj] = tv[x];
    }
    __syncthreads();

    f32x4 sf[4];
    #pragma unroll
    for (int nb = 0; nb < 4; nb++) sf[nb] = zf;
    #pragma unroll
    for (int ks = 0; ks < 2; ks++) {
      #pragma unroll
      for (int nb = 0; nb < 4; nb++) {
        bf16x8 kb = *(const bf16x8*)&Kt[(nb * 16 + col) * 72 + ks * 32 + quad * 8];
        sf[nb] = __builtin_amdgcn_mfma_f32_16x16x32_bf16(aq[ks], kb, sf[nb], 0, 0, 0);
      }
    }

    const bool diag = (jt == it);
    #pragma unroll
    for (int r = 0; r < 4; r++) {
      const int irow = i0 + w * 16 + quad * 4 + r;
      float sv[4];
      #pragma unroll
      for (int nb = 0; nb < 4; nb++) {
        float s = sf[nb][r] * 0.125f;
        if (diag && (j0 + nb * 16 + col) > irow) s = -1e30f;
        sv[nb] = s;
      }
      float rm = fmaxf(fmaxf(sv[0], sv[1]), fmaxf(sv[2], sv[3]));
      #pragma unroll
      for (int off = 8; off > 0; off >>= 1) rm = fmaxf(rm, __shfl_xor(rm, off, 64));
      const float mn = fmaxf(mrow[r], rm);
      const float alpha = __expf(mrow[r] - mn);
      mrow[r] = mn;
      float ps = 0.0f;
      #pragma unroll
      for (int nb = 0; nb < 4; nb++) {
        float p = __expf(sv[nb] - mn);
        ps += p;
        bf16 hb = f2b(p);
        Pw[(w * 16 + quad * 4 + r) * 72 + nb * 16 + col] = *(unsigned short*)&hb;
      }
      #pragma unroll
      for (int off = 8; off > 0; off >>= 1) ps += __shfl_xor(ps, off, 64);
      lrow[r] = lrow[r] * alpha + ps;
      #pragma unroll
      for (int db = 0; db < 4; db++) o[db][r] *= alpha;
    }

    #pragma unroll
    for (int ks = 0; ks < 2; ks++) {
      bf16x8 pa = *(const bf16x8*)&Pw[(w * 16 + col) * 72 + ks * 32 + quad * 8];
      #pragma unroll
      for (int db = 0; db < 4; db++) {
        bf16x8 vb = *(const bf16x8*)&Vt[(db * 16 + col) * 72 + ks * 32 + quad * 8];
        o[db] = __builtin_amdgcn_mfma_f32_16x16x32_bf16(pa, vb, o[db], 0, 0, 0);
      }
    }
  }

  unsigned short* ap = (unsigned short*)att;
  #pragma unroll
  for (int r = 0; r < 4; r++) {
    const int irow = i0 + w * 16 + quad * 4 + r;
    const float inv = 1.0f / lrow[r];
    size_t ob = ((size_t)irow * B + b) * Dm + n * DH + col;
    #pragma unroll
    for (int db = 0; db < 4; db++) {
      bf16 hb = f2b(o[db][r] * inv);
      ap[ob + db * 16] = *(unsigned short*)&hb;
    }
  }
}

// content retrieval + gated combine, and vd = k - delta (uses cK = elu(v)+1 !)
// q/k/v at qkv stride QS (offsets 0/768/1536); att/vd stride Dm.
__global__ void meminfer_kernel(const bf16* __restrict__ qkv,
                                const float* __restrict__ mem, const float* __restrict__ mnorm,
                                bf16* __restrict__ att, bf16* __restrict__ vd) {
  int wid = threadIdx.x >> 6;
  int lane = threadIdx.x & 63;
  int row = blockIdx.x * 4 + wid;      // ((s*B)+b)*NH+n
  int n = row % NH;
  int sb = row / NH;
  int baseq = sb * QS + n * DH;
  int based = sb * Dm + n * DH;
  int b = sb % B;
  float qv = b2f(qkv[baseq + lane]);
  float kv = b2f(qkv[baseq + 768 + lane]);
  float vv = b2f(qkv[baseq + 1536 + lane]);
  float cq = qv > 0.0f ? qv + 1.0f : expf(qv);   // elu+1
  float ck = vv > 0.0f ? vv + 1.0f : expf(vv);
  float nr = mnorm[(size_t)(b * NH + n) * DH + lane];
  float denq = wave_sum(cq * nr);
  float denk = wave_sum(ck * nr);
  const float* mrow = mem + (size_t)(b * NH + n) * DH * DH;
  float numq = 0.0f, numk = 0.0f;
  #pragma unroll 8
  for (int kk = 0; kk < DH; kk++) {
    float mval = mrow[(size_t)kk * DH + lane];
    numq += __shfl(cq, kk, 64) * mval;
    numk += __shfl(ck, kk, 64) * mval;
  }
  float gate = 1.0f / (1.0f + expf(-0.01f));
  float content = numq / denq;
  float delta = numk / denk;
  att[based + lane] = f2b(gate * content + (1.0f - gate) * b2f(att[based + lane]));
  vd[based + lane] = f2b(kv - delta);
}

// pass 1: part[c][bn][k*64+v] = sum_{s in chunk c} cK[s,k]*vd[s,v]
//         pnorm[c][bn][k]     = sum_{s in chunk c} cK[s,k]
// grid = B*NH*MU_CHUNK blocks; plain coalesced stores, NO atomics.
__global__ void memupd_kernel(const bf16* __restrict__ qkv, const bf16* __restrict__ vd,
                              float* __restrict__ part, float* __restrict__ pnorm) {
  int bn = blockIdx.x % (B * NH);
  int c = blockIdx.x / (B * NH);
  int b = bn / NH, n = bn % NH;
  int t = threadIdx.x;        // 256
  int k = t >> 2;             // 0..63
  int v0 = (t & 3) * 16;      // 0,16,32,48
  __shared__ float ckl[8][DH];
  __shared__ float vdl[8][DH];
  float acc[16];
  #pragma unroll
  for (int j = 0; j < 16; j++) acc[j] = 0.0f;
  float nsum = 0.0f;
  const int sBeg = c * (S / MU_CHUNK), sEnd = sBeg + S / MU_CHUNK;
  for (int s0 = sBeg; s0 < sEnd; s0 += 8) {
    #pragma unroll
    for (int i2 = 0; i2 < 2; i2++) {
      int idx = t + i2 * 256;        // 0..511
      int sp = idx >> 6, dd = idx & 63;
      int gq = ((s0 + sp) * B + b) * QS + 1536 + n * DH + dd;   // v
      int gd = ((s0 + sp) * B + b) * Dm + n * DH + dd;          // vd
      float vv = b2f(qkv[gq]);
      ckl[sp][dd] = vv > 0.0f ? vv + 1.0f : expf(vv);
      vdl[sp][dd] = b2f(vd[gd]);
    }
    __syncthreads();
    #pragma unroll
    for (int sp = 0; sp < 8; sp++) {
      float cc = ckl[sp][k];
      if ((t & 3) == 0) nsum += cc;
      #pragma unroll
      for (int j = 0; j < 16; j++) acc[j] += cc * vdl[sp][v0 + j];
    }
    __syncthreads();
  }
  float* prow = part + (size_t)c * (B * NH * DH * DH) + (size_t)bn * DH * DH;
  #pragma unroll
  for (int j4 = 0; j4 < 4; j4++) {
    float4 o;
    o.x = acc[j4 * 4 + 0]; o.y = acc[j4 * 4 + 1];
    o.z = acc[j4 * 4 + 2]; o.w = acc[j4 * 4 + 3];
    *(float4*)&prow[k * DH + v0 + j4 * 4] = o;
  }
  if ((t & 3) == 0) pnorm[(size_t)c * (B * NH * DH) + bn * DH + k] = nsum;
}

// pass 2: out_mem = mem + sum_c part[c];  out_norm = mnorm + sum_c pnorm[c]
// float4-vectorized; grid covers (786432 + 3072)/4 = 197376 threads = 771 blocks.
__global__ void memred_kernel(const float* __restrict__ mem, const float* __restrict__ mnorm,
                              const float* __restrict__ part, const float* __restrict__ pnorm,
                              float* __restrict__ out_mem, float* __restrict__ out_norm) {
  const int MEMN = B * NH * DH * DH;   // 786432
  int i = blockIdx.x * blockDim.x + threadIdx.x;
  if (i < MEMN / 4) {
    int i4 = i * 4;
    float4 a = *(const float4*)(mem + i4);
    #pragma unroll
    for (int c = 0; c < MU_CHUNK; c++) {
      float4 p = *(const float4*)(part + (size_t)c * MEMN + i4);
      a.x += p.x; a.y += p.y; a.z += p.z; a.w += p.w;
    }
    *(float4*)(out_mem + i4) = a;
  } else {
    int j4 = (i - MEMN / 4) * 4;
    if (j4 < B * NH * DH) {
      float4 a = *(const float4*)(mnorm + j4);
      #pragma unroll
      for (int c = 0; c < MU_CHUNK; c++) {
        float4 p = *(const float4*)(pnorm + (size_t)c * (B * NH * DH) + j4);
        a.x += p.x; a.y += p.y; a.z += p.z; a.w += p.w;
      }
      *(float4*)(out_norm + j4) = a;
    }
  }
}

// out = layer_norm(x + y, g, b); one block per row of 768. fp32 and/or bf16 out.
template <typename TX, typename TY>
__global__ void addln_kernel(const TX* __restrict__ x, const TY* __restrict__ y,
                             const float* __restrict__ g, const float* __restrict__ bb,
                             float* __restrict__ outf, bf16* __restrict__ outb) {
  int row = blockIdx.x;
  int t = threadIdx.x;      // 256
  float vals[3];
  float sum = 0.0f, sq = 0.0f;
  #pragma unroll
  for (int i = 0; i < 3; i++) {
    size_t idx = (size_t)row * Dm + t + i * 256;
    float vv = ldv(x, idx) + ldv(y, idx);
    vals[i] = vv;
    sum += vv;
    sq += vv * vv;
  }
  sum = wave_sum(sum);
  sq = wave_sum(sq);
  __shared__ float s1[4], s2[4];
  int w = t >> 6, lane = t & 63;
  if (lane == 0) { s1[w] = sum; s2[w] = sq; }
  __syncthreads();
  if (t == 0) {
    s1[0] = s1[0] + s1[1] + s1[2] + s1[3];
    s2[0] = s2[0] + s2[1] + s2[2] + s2[3];
  }
  __syncthreads();
  sum = s1[0]; sq = s2[0];
  float mu = sum / 768.0f;
  float var = sq / 768.0f - mu * mu;
  float rs = rsqrtf(var + 1e-5f);
  #pragma unroll
  for (int i = 0; i < 3; i++) {
    int d = t + i * 256;
    float o = (vals[i] - mu) * rs * g[d] + bb[d];
    size_t idx = (size_t)row * Dm + d;
    if (outf) outf[idx] = o;
    if (outb) outb[idx] = f2b(o);
  }
}

extern "C" void kernel_launch(void* const* d_in, const int* in_sizes, int n_in,
                              void* d_out, int out_size, void* d_ws, size_t ws_size,
                              hipStream_t stream) {
  (void)in_sizes; (void)n_in; (void)out_size; (void)ws_size;
  const int*   inp   = (const int*)d_in[0];
  const float* wemb  = (const float*)d_in[1];
  const float* Wq    = (const float*)d_in[2];
  const float* Wkv   = (const float*)d_in[3];
  const float* Wo    = (const float*)d_in[4];
  const float* ln1g  = (const float*)d_in[5];
  const float* ln1b  = (const float*)d_in[6];
  const float* fW1   = (const float*)d_in[7];
  const float* fb1   = (const float*)d_in[8];
  const float* fW2   = (const float*)d_in[9];
  const float* fb2   = (const float*)d_in[10];
  const float* ln2g  = (const float*)d_in[11];
  const float* ln2b  = (const float*)d_in[12];
  const float* mem   = (const float*)d_in[13];
  const float* mnorm = (const float*)d_in[14];

  const size_t SBD = (size_t)S * B * Dm;   // 3,145,728

  bf16* ws   = (bf16*)d_ws;
  bf16* qkv  = ws;              // slots 0-2: fused qkv, [4096][2304]
  bf16* vd   = ws + 3 * SBD;    // slot 3
  bf16* att  = ws + 4 * SBD;    // slot 4 (aliased: h_bf, ff2o — all disjoint in time)
  bf16* hbf  = att;
  bf16* ff2o = att;
  bf16* out1 = ws + 5 * SBD;    // slot 5
  bf16* wb   = ws + 6 * SBD;    // bf16 weight pack for current layer (7,077,888 elems)
  bf16* ffm  = ws;              // 4*SBD: aliases slots 0-3 (dead by FF1)
  bf16* tmp  = ws;              // Wo-GEMM out (qkv dead after memupd)
  // memupd partials: out1 slot is dead during memupd (written later by addln).
  // 8 chunks x 48 bn x 4096 fp32 = 6,291,456 B = exactly the out1 slot.
  float* part  = (float*)out1;
  float* pnorm = (float*)(wb + SEG_END);   // 8 x 48 x 64 fp32 = 96 KiB past wb

  float* h    = (float*)d_out;  // residual stream lives in d_out (fp32)
  float* outm = h + SBD;
  float* outn = outm + (size_t)NL * B * NH * DH * DH;

  dim3 b256(256);
  embed_kernel<<<dim3((S * B * Dm + 255) / 256), b256, 0, stream>>>(inp, wemb, h, hbf);

  for (int l = 0; l < NL; l++) {
    convw_kernel<<<dim3(SEG_END / 4 / 256), b256, 0, stream>>>(
        Wq + (size_t)l * Dm * Dm, Wkv + (size_t)l * 2 * Dm * Dm,
        Wo + (size_t)l * Dm * Dm, fW1 + (size_t)l * DI * Dm,
        fW2 + (size_t)l * Dm * DI, wb);
    const bf16* wqkv = wb;
    const bf16* wo_b = wb + SEG_QKV;
    const bf16* w1_b = wb + SEG_WO;
    const bf16* w2_b = wb + SEG_W1;
    const float* mem_l = mem + (size_t)l * B * NH * DH * DH;
    const float* mn_l  = mnorm + (size_t)l * B * NH * DH;
    float* outm_l = outm + (size_t)l * B * NH * DH * DH;
    float* outn_l = outn + (size_t)l * B * NH * DH;

    // fused QKV: M=4096, N=2304, K=768 -> 576 blocks
    gemm_async<4, 0><<<dim3(QS / 128, 32), b256, 0, stream>>>(hbf, wqkv, nullptr, qkv, QS, Dm);

    attn_flash<<<dim3(S / 64, B * NH), b256, 0, stream>>>(qkv, qkv + 768, qkv + 1536, att);
    meminfer_kernel<<<dim3(S * B * NH / 4), b256, 0, stream>>>(qkv, mem_l, mn_l, att, vd);
    memupd_kernel<<<dim3(B * NH * MU_CHUNK), b256, 0, stream>>>(qkv, vd, part, pnorm);
    memred_kernel<<<dim3(771), b256, 0, stream>>>(mem_l, mn_l, part, pnorm, outm_l, outn_l);

    // Wo: N=768 -> BM=64 tile, 384 blocks
    gemm_async<2, 0><<<dim3(Dm / 128, 64), b256, 0, stream>>>(att, wo_b, nullptr, tmp, Dm, Dm);
    addln_kernel<float, bf16><<<dim3(S * B), b256, 0, stream>>>(
        h, tmp, ln1g + l * Dm, ln1b + l * Dm, nullptr, out1);

    // FF1: M=4096, N=3072, K=768 -> 768 blocks
    gemm_async<4, 1><<<dim3(DI / 128, 32), b256, 0, stream>>>(out1, w1_b, fb1 + (size_t)l * DI,
                                                              ffm, DI, Dm);
    // FF2: N=768, K=3072 -> BM=64 tile, 384 blocks
    gemm_async<2, 0><<<dim3(Dm / 128, 64), b256, 0, stream>>>(ffm, w2_b, fb2 + (size_t)l * Dm,
                                                              ff2o, Dm, DI);
    addln_kernel<bf16, bf16><<<dim3(S * B), b256, 0, stream>>>(
        out1, ff2o, ln2g + l * Dm, ln2b + l * Dm, h, hbf);
  }
}

// Round 4
// 1375.177 us; speedup vs baseline: 1.6428x; 1.1751x over previous
//
#include <hip/hip_runtime.h>
#include <hip/hip_bf16.h>
#include <math.h>

#define S 1024
#define B 4
#define Dm 768
#define NH 12
#define DH 64
#define NL 4
#define DI 3072
#define QS 2304   // row stride of fused qkv activation buffer
#define MU_CHUNK 8   // S-dim split for memupd (partials fit exactly in out1 slot)

typedef __hip_bfloat16 bf16;
typedef short bf16x8 __attribute__((ext_vector_type(8)));
typedef float f32x4 __attribute__((ext_vector_type(4)));

__device__ __forceinline__ float b2f(bf16 x) { return __bfloat162float(x); }
__device__ __forceinline__ bf16 f2b(float x) { return __float2bfloat16(x); }

__device__ __forceinline__ float ldv(const float* p, size_t i) { return p[i]; }
__device__ __forceinline__ float ldv(const bf16* p, size_t i) { return b2f(p[i]); }

__device__ __forceinline__ float wave_sum(float x) {
  #pragma unroll
  for (int off = 32; off > 0; off >>= 1) x += __shfl_xor(x, off, 64);
  return x;
}

// async 16B global -> LDS DMA. LDS dest = wave-uniform base + lane*16.
typedef const __attribute__((address_space(1))) unsigned int guint;
typedef __attribute__((address_space(3))) unsigned int luint;
__device__ __forceinline__ void async_cp16(const void* g, void* l) {
  __builtin_amdgcn_global_load_lds((guint*)g, (luint*)l, 16, 0, 0);
}

// h[s,b,d] = word_emb[inp[s,b], d] * sqrt(D) + pos_emb(s, d); fp32 + bf16 copies
__global__ void embed_kernel(const int* __restrict__ inp, const float* __restrict__ wemb,
                             float* __restrict__ h, bf16* __restrict__ hb) {
  int idx = blockIdx.x * blockDim.x + threadIdx.x;
  if (idx >= S * B * Dm) return;
  int d = idx % Dm;
  int sb = idx / Dm;
  int b = sb % B;
  int s = sb / B;
  int tok = inp[s * B + b];
  float e = wemb[(size_t)tok * Dm + d] * 27.712812921102035f; // sqrt(768)
  float ps = (float)(S - 1 - s);
  float pe;
  if (d < Dm / 2) {
    float invf = expf(-(2.0f * (float)d / (float)Dm) * 9.210340371976184f); // ln(10000)
    pe = sinf(ps * invf);
  } else {
    int j = d - Dm / 2;
    float invf = expf(-(2.0f * (float)j / (float)Dm) * 9.210340371976184f);
    pe = cosf(ps * invf);
  }
  float val = e + pe;
  h[idx] = val;
  hb[idx] = f2b(val);
}

// pack one layer's weights to bf16 into wb:
//   [qkv 2304x768 | wo 768x768 | w1 3072x768 | w2 768x3072]  (all B^T, K contiguous)
#define SEG_QKV 1769472
#define SEG_WO  2359296
#define SEG_W1  4718592
#define SEG_END 7077888
__global__ void convw_kernel(const float* __restrict__ Wq, const float* __restrict__ Wkv,
                             const float* __restrict__ Wo, const float* __restrict__ W1,
                             const float* __restrict__ W2, bf16* __restrict__ dst) {
  int idx = (blockIdx.x * blockDim.x + threadIdx.x) * 4;
  if (idx >= SEG_END) return;
  const float* src;
  if (idx < SEG_QKV) {
    src = (idx < 589824) ? Wq + idx : Wkv + (idx - 589824);
  } else if (idx < SEG_WO) {
    src = Wo + (idx - SEG_QKV);
  } else if (idx < SEG_W1) {
    src = W1 + (idx - SEG_WO);
  } else {
    src = W2 + (idx - SEG_W1);
  }
  float4 f = *(const float4*)src;
  bf16 b0 = f2b(f.x), b1 = f2b(f.y), b2 = f2b(f.z), b3 = f2b(f.w);
  unsigned short o[4];
  o[0] = *(unsigned short*)&b0; o[1] = *(unsigned short*)&b1;
  o[2] = *(unsigned short*)&b2; o[3] = *(unsigned short*)&b3;
  *(uint2*)((unsigned short*)dst + idx) = *(uint2*)o;
}

// C[M,N] = A[M,K] @ W[N,K]^T (+bias)(+relu). bf16 in, fp32 acc, bf16 out.
// 256 thr = 4 waves (2x2). BN=128, BM=32*MREP (128 or 64), BK=32.
// LDS layout = MFMA-fragment order: 16-row tile T (1KB) holds elem (m,k) at
// T*512 + (k>>3)*128 + (m&15)*8 + (k&7). global_load_lds writes linearly
// (lane*16B), so the per-lane GLOBAL source is pre-swizzled to match:
//   issue i, wave w, lane l  ->  row = i*64 + w*16 + (l&15), k = (l>>4)*8.
template <int MREP, int RELU>
__global__ __launch_bounds__(256) void gemm_async(const bf16* __restrict__ A,
                                                  const bf16* __restrict__ W,
                                                  const float* __restrict__ bias,
                                                  bf16* __restrict__ C,
                                                  int ldc, int K) {
  constexpr int BM = MREP * 32;
  __shared__ __align__(16) unsigned short Asm[BM * 32];
  __shared__ __align__(16) unsigned short Bsm[128 * 32];
  const int t = threadIdx.x;
  const int w = t >> 6, lane = t & 63;
  const int col = lane & 15, quad = lane >> 4;
  const int wm = w >> 1, wn = w & 1;
  const int m0 = blockIdx.y * BM, n0 = blockIdx.x * 128;

  const bf16* aSrc = A + (size_t)(m0 + w * 16 + col) * K + quad * 8;
  const bf16* bSrc = W + (size_t)(n0 + w * 16 + col) * K + quad * 8;

  const f32x4 zf = {0.0f, 0.0f, 0.0f, 0.0f};
  f32x4 acc[MREP][4];
  #pragma unroll
  for (int mt = 0; mt < MREP; mt++)
    #pragma unroll
    for (int nt = 0; nt < 4; nt++) acc[mt][nt] = zf;

  for (int kk = 0; kk < K; kk += 32) {
    __syncthreads();                 // prior iteration's frag reads complete
    #pragma unroll
    for (int i = 0; i < MREP / 2; i++)
      async_cp16(aSrc + kk + (size_t)i * 64 * K, &Asm[i * 2048 + w * 512]);
    #pragma unroll
    for (int i = 0; i < 2; i++)
      async_cp16(bSrc + kk + (size_t)i * 64 * K, &Bsm[i * 2048 + w * 512]);
    __syncthreads();                 // compiler drains vmcnt(0) before barrier
    bf16x8 af[MREP], bfr[4];
    #pragma unroll
    for (int mt = 0; mt < MREP; mt++)
      af[mt] = *(const bf16x8*)&Asm[(wm * MREP + mt) * 512 + lane * 8];
    #pragma unroll
    for (int nt = 0; nt < 4; nt++)
      bfr[nt] = *(const bf16x8*)&Bsm[(wn * 4 + nt) * 512 + lane * 8];
    #pragma unroll
    for (int mt = 0; mt < MREP; mt++)
      #pragma unroll
      for (int nt = 0; nt < 4; nt++)
        acc[mt][nt] = __builtin_amdgcn_mfma_f32_16x16x32_bf16(af[mt], bfr[nt],
                                                              acc[mt][nt], 0, 0, 0);
  }

  #pragma unroll
  for (int nt = 0; nt < 4; nt++) {
    const int colg = n0 + wn * 64 + nt * 16 + col;
    const float bv = bias ? bias[colg] : 0.0f;
    #pragma unroll
    for (int mt = 0; mt < MREP; mt++) {
      #pragma unroll
      for (int r = 0; r < 4; r++) {
        const int row = m0 + wm * (MREP * 16) + mt * 16 + quad * 4 + r;
        float val = acc[mt][nt][r] + bv;
        if (RELU) val = fmaxf(val, 0.0f);
        C[(size_t)row * ldc + colg] = f2b(val);
      }
    }
  }
}

// Flash attention with MFMA. Block = 256 thr = 4 waves; one 64-row Q tile per (b,n).
// q/k/v read from fused qkv buffer (row stride QS); att written with stride Dm.
__global__ __launch_bounds__(256) void attn_flash(const bf16* __restrict__ q,
                                                  const bf16* __restrict__ k,
                                                  const bf16* __restrict__ v,
                                                  bf16* __restrict__ att) {
  const int it = blockIdx.x;       // q-tile index (16)
  const int bn = blockIdx.y;       // b*NH+n (48)
  const int b = bn / NH, n = bn % NH;
  const int t = threadIdx.x;
  const int w = t >> 6, lane = t & 63;
  const int col = lane & 15, quad = lane >> 4;
  const int i0 = it * 64;

  __shared__ __align__(16) unsigned short Kt[64 * 72];  // K[j][d], row stride 72
  __shared__ __align__(16) unsigned short Vt[64 * 72];  // V^T[d][j]
  __shared__ __align__(16) unsigned short Pw[64 * 72];  // per-wave P rows

  const unsigned short* qp = (const unsigned short*)q;
  const unsigned short* kp = (const unsigned short*)k;
  const unsigned short* vp = (const unsigned short*)v;

  bf16x8 aq[2];
  {
    size_t qb = ((size_t)(i0 + w * 16 + col) * B + b) * QS + n * DH + quad * 8;
    aq[0] = *(const bf16x8*)(qp + qb);
    aq[1] = *(const bf16x8*)(qp + qb + 32);
  }

  const f32x4 zf = {0.0f, 0.0f, 0.0f, 0.0f};
  float mrow[4], lrow[4];
  f32x4 o[4];
  #pragma unroll
  for (int r = 0; r < 4; r++) { mrow[r] = -1e30f; lrow[r] = 0.0f; }
  #pragma unroll
  for (int db = 0; db < 4; db++) o[db] = zf;

  const int jj = t >> 2;           // 0..63 (staging row)
  const int d0 = (t & 3) << 4;     // 0,16,32,48

  for (int jt = 0; jt <= it; jt++) {
    const int j0 = jt * 64;
    __syncthreads();
    {
      size_t gb = ((size_t)(j0 + jj) * B + b) * QS + n * DH + d0;
      *(uint4*)&Kt[jj * 72 + d0] = *(const uint4*)(kp + gb);
      *(uint4*)&Kt[jj * 72 + d0 + 8] = *(const uint4*)(kp + gb + 8);
      unsigned short tv[16];
      *(uint4*)tv = *(const uint4*)(vp + gb);
      *(uint4*)(tv + 8) = *(const uint4*)(vp + gb + 8);
      #pragma unroll
      for (int x = 0; x < 16; x++) Vt[(d0 + x) * 72 + jj] = tv[x];
    }
    __syncthreads();

    f32x4 sf[4];
    #pragma unroll
    for (int nb = 0; nb < 4; nb++) sf[nb] = zf;
    #pragma unroll
    for (int ks = 0; ks < 2; ks++) {
      #pragma unroll
      for (int nb = 0; nb < 4; nb++) {
        bf16x8 kb = *(const bf16x8*)&Kt[(nb * 16 + col) * 72 + ks * 32 + quad * 8];
        sf[nb] = __builtin_amdgcn_mfma_f32_16x16x32_bf16(aq[ks], kb, sf[nb], 0, 0, 0);
      }
    }

    const bool diag = (jt == it);
    #pragma unroll
    for (int r = 0; r < 4; r++) {
      const int irow = i0 + w * 16 + quad * 4 + r;
      float sv[4];
      #pragma unroll
      for (int nb = 0; nb < 4; nb++) {
        float s = sf[nb][r] * 0.125f;
        if (diag && (j0 + nb * 16 + col) > irow) s = -1e30f;
        sv[nb] = s;
      }
      float rm = fmaxf(fmaxf(sv[0], sv[1]), fmaxf(sv[2], sv[3]));
      #pragma unroll
      for (int off = 8; off > 0; off >>= 1) rm = fmaxf(rm, __shfl_xor(rm, off, 64));
      const float mn = fmaxf(mrow[r], rm);
      const float alpha = __expf(mrow[r] - mn);
      mrow[r] = mn;
      float ps = 0.0f;
      #pragma unroll
      for (int nb = 0; nb < 4; nb++) {
        float p = __expf(sv[nb] - mn);
        ps += p;
        bf16 hb = f2b(p);
        Pw[(w * 16 + quad * 4 + r) * 72 + nb * 16 + col] = *(unsigned short*)&hb;
      }
      #pragma unroll
      for (int off = 8; off > 0; off >>= 1) ps += __shfl_xor(ps, off, 64);
      lrow[r] = lrow[r] * alpha + ps;
      #pragma unroll
      for (int db = 0; db < 4; db++) o[db][r] *= alpha;
    }

    #pragma unroll
    for (int ks = 0; ks < 2; ks++) {
      bf16x8 pa = *(const bf16x8*)&Pw[(w * 16 + col) * 72 + ks * 32 + quad * 8];
      #pragma unroll
      for (int db = 0; db < 4; db++) {
        bf16x8 vb = *(const bf16x8*)&Vt[(db * 16 + col) * 72 + ks * 32 + quad * 8];
        o[db] = __builtin_amdgcn_mfma_f32_16x16x32_bf16(pa, vb, o[db], 0, 0, 0);
      }
    }
  }

  unsigned short* ap = (unsigned short*)att;
  #pragma unroll
  for (int r = 0; r < 4; r++) {
    const int irow = i0 + w * 16 + quad * 4 + r;
    const float inv = 1.0f / lrow[r];
    size_t ob = ((size_t)irow * B + b) * Dm + n * DH + col;
    #pragma unroll
    for (int db = 0; db < 4; db++) {
      bf16 hb = f2b(o[db][r] * inv);
      ap[ob + db * 16] = *(unsigned short*)&hb;
    }
  }
}

// MFMA meminfer: per (b,n), num[s,v] = cQ[s,:]@mem[:,v], den[s] = cQ[s,:]@mnorm
// (and same with cK for delta). B operand = mem^T in fragment layout, with a 5th
// 16-row tile whose row 0 is mnorm -> dens fall out of the same MFMAs (col 64).
// Grid: 16 s-tiles (64 rows) x 48 bn = 768 blocks, 256 thr = 4 waves.
// Then: att = gate*num/den + (1-gate)*att;  vd = k - numk/denk.
__global__ __launch_bounds__(256) void meminfer_mfma(const bf16* __restrict__ qkv,
                                                     const float* __restrict__ mem,
                                                     const float* __restrict__ mnorm,
                                                     bf16* __restrict__ att,
                                                     bf16* __restrict__ vd) {
  const int s0 = blockIdx.x * 64;
  const int bn = blockIdx.y;
  const int b = bn / NH, n = bn % NH;
  const int t = threadIdx.x;
  const int w = t >> 6, lane = t & 63;
  const int col = lane & 15, quad = lane >> 4;

  // fragment layout addr(row,k) = (row>>4)*1024 + (k>>5)*512 + ((k&31)>>3)*128
  //                              + (row&15)*8 + (k&7)
  __shared__ __align__(16) unsigned short CQ[4096];   // cQ rows 0..63, k 0..63
  __shared__ __align__(16) unsigned short CK[4096];   // cK rows
  __shared__ __align__(16) unsigned short Bm[5120];   // mem^T (4 tiles) + mnorm tile

  const unsigned short* qp = (const unsigned short*)qkv;

  // stage cQ/cK: thread handles row r = t>>2, 16 k at k0 = (t&3)*16
  {
    int r = t >> 2;
    int k0 = (t & 3) * 16;
    size_t gb = ((size_t)(s0 + r) * B + b) * QS + n * DH + k0;
    int abase = (r >> 4) * 1024 + (k0 >> 5) * 512 + ((k0 & 31) >> 3) * 128 + (r & 15) * 8;
    unsigned short tq[16], tv[16], oq[16], ov[16];
    *(uint4*)tq = *(const uint4*)(qp + gb);
    *(uint4*)(tq + 8) = *(const uint4*)(qp + gb + 8);
    *(uint4*)tv = *(const uint4*)(qp + gb + 1536);
    *(uint4*)(tv + 8) = *(const uint4*)(qp + gb + 1536 + 8);
    #pragma unroll
    for (int i = 0; i < 16; i++) {
      float fq = b2f(*(const bf16*)&tq[i]);
      float fv = b2f(*(const bf16*)&tv[i]);
      float eq = fq > 0.0f ? fq + 1.0f : __expf(fq);
      float ev = fv > 0.0f ? fv + 1.0f : __expf(fv);
      bf16 bq = f2b(eq), bv2 = f2b(ev);
      oq[i] = *(unsigned short*)&bq;
      ov[i] = *(unsigned short*)&bv2;
    }
    *(bf16x8*)&CQ[abase] = *(bf16x8*)oq;
    *(bf16x8*)&CQ[abase + 128] = *(bf16x8*)(oq + 8);
    *(bf16x8*)&CK[abase] = *(bf16x8*)ov;
    *(bf16x8*)&CK[abase + 128] = *(bf16x8*)(ov + 8);
  }
  // stage mem^T: thread handles column v = t&63, 16 k at kb = (t>>6)*16
  {
    int v = t & 63, kb = (t >> 6) * 16;
    const float* mp = mem + (size_t)bn * DH * DH;
    #pragma unroll
    for (int i = 0; i < 16; i++) {
      int k = kb + i;
      bf16 mb = f2b(mp[(size_t)k * DH + v]);
      int addr = (v >> 4) * 1024 + (k >> 5) * 512 + ((k & 31) >> 3) * 128 + (v & 15) * 8 + (k & 7);
      Bm[addr] = *(unsigned short*)&mb;
    }
  }
  // stage mnorm tile (tile 4): row 0 = mnorm, rows 1..15 = 0
  {
    int a = t * 4;                       // 4 consecutive shorts within tile 4
    int m = (a >> 3) & 15;
    int kk = (a >> 9) * 32 + ((a >> 7) & 3) * 8 + (a & 7);
    unsigned short vals[4] = {0, 0, 0, 0};
    if (m == 0) {
      const float* np = mnorm + (size_t)bn * DH;
      #pragma unroll
      for (int j = 0; j < 4; j++) {
        bf16 nb = f2b(np[kk + j]);
        vals[j] = *(unsigned short*)&nb;
      }
    }
    *(uint2*)&Bm[4096 + a] = *(uint2*)vals;
  }
  __syncthreads();

  const f32x4 zf = {0.0f, 0.0f, 0.0f, 0.0f};
  f32x4 aq[5], ak[5];
  #pragma unroll
  for (int nb = 0; nb < 5; nb++) { aq[nb] = zf; ak[nb] = zf; }
  #pragma unroll
  for (int ks = 0; ks < 2; ks++) {
    bf16x8 fq = *(const bf16x8*)&CQ[w * 1024 + ks * 512 + lane * 8];
    bf16x8 fk = *(const bf16x8*)&CK[w * 1024 + ks * 512 + lane * 8];
    #pragma unroll
    for (int nb = 0; nb < 5; nb++) {
      bf16x8 bm = *(const bf16x8*)&Bm[nb * 1024 + ks * 512 + lane * 8];
      aq[nb] = __builtin_amdgcn_mfma_f32_16x16x32_bf16(fq, bm, aq[nb], 0, 0, 0);
      ak[nb] = __builtin_amdgcn_mfma_f32_16x16x32_bf16(fk, bm, ak[nb], 0, 0, 0);
    }
  }

  const float gate = 1.0f / (1.0f + expf(-0.01f));
  unsigned short* ap = (unsigned short*)att;
  unsigned short* vp2 = (unsigned short*)vd;
  #pragma unroll
  for (int r = 0; r < 4; r++) {
    const int srow = s0 + w * 16 + quad * 4 + r;
    const float denq = __shfl(aq[4][r], lane & 48, 64);   // col 64 (den) lives at col==0
    const float denk = __shfl(ak[4][r], lane & 48, 64);
    const size_t bd = ((size_t)srow * B + b) * Dm + n * DH + col;
    const size_t bq = ((size_t)srow * B + b) * QS + 768 + n * DH + col;
    #pragma unroll
    for (int nb = 0; nb < 4; nb++) {
      float content = aq[nb][r] / denq;
      float delta = ak[nb][r] / denk;
      float attv = b2f(*(const bf16*)&ap[bd + nb * 16]);
      bf16 ao = f2b(gate * content + (1.0f - gate) * attv);
      ap[bd + nb * 16] = *(unsigned short*)&ao;
      float kvv = b2f(*(const bf16*)&qp[bq + nb * 16]);
      bf16 vo = f2b(kvv - delta);
      vp2[bd + nb * 16] = *(unsigned short*)&vo;
    }
  }
}

// pass 1: part[c][bn][k*64+v] = sum_{s in chunk c} cK[s,k]*vd[s,v]
//         pnorm[c][bn][k]     = sum_{s in chunk c} cK[s,k]
// grid = B*NH*MU_CHUNK blocks; plain coalesced stores, NO atomics.
__global__ void memupd_kernel(const bf16* __restrict__ qkv, const bf16* __restrict__ vd,
                              float* __restrict__ part, float* __restrict__ pnorm) {
  int bn = blockIdx.x % (B * NH);
  int c = blockIdx.x / (B * NH);
  int b = bn / NH, n = bn % NH;
  int t = threadIdx.x;        // 256
  int k = t >> 2;             // 0..63
  int v0 = (t & 3) * 16;      // 0,16,32,48
  __shared__ float ckl[8][DH];
  __shared__ float vdl[8][DH];
  float acc[16];
  #pragma unroll
  for (int j = 0; j < 16; j++) acc[j] = 0.0f;
  float nsum = 0.0f;
  const int sBeg = c * (S / MU_CHUNK), sEnd = sBeg + S / MU_CHUNK;
  for (int s0 = sBeg; s0 < sEnd; s0 += 8) {
    #pragma unroll
    for (int i2 = 0; i2 < 2; i2++) {
      int idx = t + i2 * 256;        // 0..511
      int sp = idx >> 6, dd = idx & 63;
      int gq = ((s0 + sp) * B + b) * QS + 1536 + n * DH + dd;   // v
      int gd = ((s0 + sp) * B + b) * Dm + n * DH + dd;          // vd
      float vv = b2f(qkv[gq]);
      ckl[sp][dd] = vv > 0.0f ? vv + 1.0f : expf(vv);
      vdl[sp][dd] = b2f(vd[gd]);
    }
    __syncthreads();
    #pragma unroll
    for (int sp = 0; sp < 8; sp++) {
      float cc = ckl[sp][k];
      if ((t & 3) == 0) nsum += cc;
      #pragma unroll
      for (int j = 0; j < 16; j++) acc[j] += cc * vdl[sp][v0 + j];
    }
    __syncthreads();
  }
  float* prow = part + (size_t)c * (B * NH * DH * DH) + (size_t)bn * DH * DH;
  #pragma unroll
  for (int j4 = 0; j4 < 4; j4++) {
    float4 o;
    o.x = acc[j4 * 4 + 0]; o.y = acc[j4 * 4 + 1];
    o.z = acc[j4 * 4 + 2]; o.w = acc[j4 * 4 + 3];
    *(float4*)&prow[k * DH + v0 + j4 * 4] = o;
  }
  if ((t & 3) == 0) pnorm[(size_t)c * (B * NH * DH) + bn * DH + k] = nsum;
}

// pass 2: out_mem = mem + sum_c part[c];  out_norm = mnorm + sum_c pnorm[c]
// float4-vectorized; grid covers (786432 + 3072)/4 = 197376 threads = 771 blocks.
__global__ void memred_kernel(const float* __restrict__ mem, const float* __restrict__ mnorm,
                              const float* __restrict__ part, const float* __restrict__ pnorm,
                              float* __restrict__ out_mem, float* __restrict__ out_norm) {
  const int MEMN = B * NH * DH * DH;   // 786432
  int i = blockIdx.x * blockDim.x + threadIdx.x;
  if (i < MEMN / 4) {
    int i4 = i * 4;
    float4 a = *(const float4*)(mem + i4);
    #pragma unroll
    for (int c = 0; c < MU_CHUNK; c++) {
      float4 p = *(const float4*)(part + (size_t)c * MEMN + i4);
      a.x += p.x; a.y += p.y; a.z += p.z; a.w += p.w;
    }
    *(float4*)(out_mem + i4) = a;
  } else {
    int j4 = (i - MEMN / 4) * 4;
    if (j4 < B * NH * DH) {
      float4 a = *(const float4*)(mnorm + j4);
      #pragma unroll
      for (int c = 0; c < MU_CHUNK; c++) {
        float4 p = *(const float4*)(pnorm + (size_t)c * (B * NH * DH) + j4);
        a.x += p.x; a.y += p.y; a.z += p.z; a.w += p.w;
      }
      *(float4*)(out_norm + j4) = a;
    }
  }
}

// out = layer_norm(x + y, g, b); one block per row of 768. fp32 and/or bf16 out.
template <typename TX, typename TY>
__global__ void addln_kernel(const TX* __restrict__ x, const TY* __restrict__ y,
                             const float* __restrict__ g, const float* __restrict__ bb,
                             float* __restrict__ outf, bf16* __restrict__ outb) {
  int row = blockIdx.x;
  int t = threadIdx.x;      // 256
  float vals[3];
  float sum = 0.0f, sq = 0.0f;
  #pragma unroll
  for (int i = 0; i < 3; i++) {
    size_t idx = (size_t)row * Dm + t + i * 256;
    float vv = ldv(x, idx) + ldv(y, idx);
    vals[i] = vv;
    sum += vv;
    sq += vv * vv;
  }
  sum = wave_sum(sum);
  sq = wave_sum(sq);
  __shared__ float s1[4], s2[4];
  int w = t >> 6, lane = t & 63;
  if (lane == 0) { s1[w] = sum; s2[w] = sq; }
  __syncthreads();
  if (t == 0) {
    s1[0] = s1[0] + s1[1] + s1[2] + s1[3];
    s2[0] = s2[0] + s2[1] + s2[2] + s2[3];
  }
  __syncthreads();
  sum = s1[0]; sq = s2[0];
  float mu = sum / 768.0f;
  float var = sq / 768.0f - mu * mu;
  float rs = rsqrtf(var + 1e-5f);
  #pragma unroll
  for (int i = 0; i < 3; i++) {
    int d = t + i * 256;
    float o = (vals[i] - mu) * rs * g[d] + bb[d];
    size_t idx = (size_t)row * Dm + d;
    if (outf) outf[idx] = o;
    if (outb) outb[idx] = f2b(o);
  }
}

extern "C" void kernel_launch(void* const* d_in, const int* in_sizes, int n_in,
                              void* d_out, int out_size, void* d_ws, size_t ws_size,
                              hipStream_t stream) {
  (void)in_sizes; (void)n_in; (void)out_size; (void)ws_size;
  const int*   inp   = (const int*)d_in[0];
  const float* wemb  = (const float*)d_in[1];
  const float* Wq    = (const float*)d_in[2];
  const float* Wkv   = (const float*)d_in[3];
  const float* Wo    = (const float*)d_in[4];
  const float* ln1g  = (const float*)d_in[5];
  const float* ln1b  = (const float*)d_in[6];
  const float* fW1   = (const float*)d_in[7];
  const float* fb1   = (const float*)d_in[8];
  const float* fW2   = (const float*)d_in[9];
  const float* fb2   = (const float*)d_in[10];
  const float* ln2g  = (const float*)d_in[11];
  const float* ln2b  = (const float*)d_in[12];
  const float* mem   = (const float*)d_in[13];
  const float* mnorm = (const float*)d_in[14];

  const size_t SBD = (size_t)S * B * Dm;   // 3,145,728

  bf16* ws   = (bf16*)d_ws;
  bf16* qkv  = ws;              // slots 0-2: fused qkv, [4096][2304]
  bf16* vd   = ws + 3 * SBD;    // slot 3
  bf16* att  = ws + 4 * SBD;    // slot 4 (aliased: h_bf, ff2o — all disjoint in time)
  bf16* hbf  = att;
  bf16* ff2o = att;
  bf16* out1 = ws + 5 * SBD;    // slot 5
  bf16* wb   = ws + 6 * SBD;    // bf16 weight pack for current layer (7,077,888 elems)
  bf16* ffm  = ws;              // 4*SBD: aliases slots 0-3 (dead by FF1)
  bf16* tmp  = ws;              // Wo-GEMM out (qkv dead after memupd)
  // memupd partials: out1 slot is dead during memupd (written later by addln).
  // 8 chunks x 48 bn x 4096 fp32 = 6,291,456 B = exactly the out1 slot.
  float* part  = (float*)out1;
  float* pnorm = (float*)(wb + SEG_END);   // 8 x 48 x 64 fp32 = 96 KiB past wb

  float* h    = (float*)d_out;  // residual stream lives in d_out (fp32)
  float* outm = h + SBD;
  float* outn = outm + (size_t)NL * B * NH * DH * DH;

  dim3 b256(256);
  embed_kernel<<<dim3((S * B * Dm + 255) / 256), b256, 0, stream>>>(inp, wemb, h, hbf);

  for (int l = 0; l < NL; l++) {
    convw_kernel<<<dim3(SEG_END / 4 / 256), b256, 0, stream>>>(
        Wq + (size_t)l * Dm * Dm, Wkv + (size_t)l * 2 * Dm * Dm,
        Wo + (size_t)l * Dm * Dm, fW1 + (size_t)l * DI * Dm,
        fW2 + (size_t)l * Dm * DI, wb);
    const bf16* wqkv = wb;
    const bf16* wo_b = wb + SEG_QKV;
    const bf16* w1_b = wb + SEG_WO;
    const bf16* w2_b = wb + SEG_W1;
    const float* mem_l = mem + (size_t)l * B * NH * DH * DH;
    const float* mn_l  = mnorm + (size_t)l * B * NH * DH;
    float* outm_l = outm + (size_t)l * B * NH * DH * DH;
    float* outn_l = outn + (size_t)l * B * NH * DH;

    // fused QKV: M=4096, N=2304, K=768 -> 576 blocks
    gemm_async<4, 0><<<dim3(QS / 128, 32), b256, 0, stream>>>(hbf, wqkv, nullptr, qkv, QS, Dm);

    attn_flash<<<dim3(S / 64, B * NH), b256, 0, stream>>>(qkv, qkv + 768, qkv + 1536, att);
    meminfer_mfma<<<dim3(S / 64, B * NH), b256, 0, stream>>>(qkv, mem_l, mn_l, att, vd);
    memupd_kernel<<<dim3(B * NH * MU_CHUNK), b256, 0, stream>>>(qkv, vd, part, pnorm);
    memred_kernel<<<dim3(771), b256, 0, stream>>>(mem_l, mn_l, part, pnorm, outm_l, outn_l);

    // Wo: N=768 -> BM=64 tile, 384 blocks
    gemm_async<2, 0><<<dim3(Dm / 128, 64), b256, 0, stream>>>(att, wo_b, nullptr, tmp, Dm, Dm);
    addln_kernel<float, bf16><<<dim3(S * B), b256, 0, stream>>>(
        h, tmp, ln1g + l * Dm, ln1b + l * Dm, nullptr, out1);

    // FF1: M=4096, N=3072, K=768 -> 768 blocks
    gemm_async<4, 1><<<dim3(DI / 128, 32), b256, 0, stream>>>(out1, w1_b, fb1 + (size_t)l * DI,
                                                              ffm, DI, Dm);
    // FF2: N=768, K=3072 -> BM=64 tile, 384 blocks
    gemm_async<2, 0><<<dim3(Dm / 128, 64), b256, 0, stream>>>(ffm, w2_b, fb2 + (size_t)l * Dm,
                                                              ff2o, Dm, DI);
    addln_kernel<bf16, bf16><<<dim3(S * B), b256, 0, stream>>>(
        out1, ff2o, ln2g + l * Dm, ln2b + l * Dm, h, hbf);
  }
}

// Round 5
// 1326.212 us; speedup vs baseline: 1.7034x; 1.0369x over previous
//
#include <hip/hip_runtime.h>
#include <hip/hip_bf16.h>
#include <math.h>

#define S 1024
#define B 4
#define Dm 768
#define NH 12
#define DH 64
#define NL 4
#define DI 3072
#define QS 2304   // row stride of fused qkv activation buffer
#define MU_CHUNK 8   // S-dim split for memupd (partials fit exactly in out1 slot)

typedef __hip_bfloat16 bf16;
typedef short bf16x8 __attribute__((ext_vector_type(8)));
typedef float f32x4 __attribute__((ext_vector_type(4)));

__device__ __forceinline__ float b2f(bf16 x) { return __bfloat162float(x); }
__device__ __forceinline__ bf16 f2b(float x) { return __float2bfloat16(x); }

__device__ __forceinline__ float ldv(const float* p, size_t i) { return p[i]; }
__device__ __forceinline__ float ldv(const bf16* p, size_t i) { return b2f(p[i]); }

__device__ __forceinline__ float wave_sum(float x) {
  #pragma unroll
  for (int off = 32; off > 0; off >>= 1) x += __shfl_xor(x, off, 64);
  return x;
}

// async 16B global -> LDS DMA. LDS dest = wave-uniform base + lane*16.
typedef const __attribute__((address_space(1))) unsigned int guint;
typedef __attribute__((address_space(3))) unsigned int luint;
__device__ __forceinline__ void async_cp16(const void* g, void* l) {
  __builtin_amdgcn_global_load_lds((guint*)g, (luint*)l, 16, 0, 0);
}

// h[s,b,d] = word_emb[inp[s,b], d] * sqrt(D) + pos_emb(s, d); fp32 + bf16 copies
__global__ void embed_kernel(const int* __restrict__ inp, const float* __restrict__ wemb,
                             float* __restrict__ h, bf16* __restrict__ hb) {
  int idx = blockIdx.x * blockDim.x + threadIdx.x;
  if (idx >= S * B * Dm) return;
  int d = idx % Dm;
  int sb = idx / Dm;
  int b = sb % B;
  int s = sb / B;
  int tok = inp[s * B + b];
  float e = wemb[(size_t)tok * Dm + d] * 27.712812921102035f; // sqrt(768)
  float ps = (float)(S - 1 - s);
  float pe;
  if (d < Dm / 2) {
    float invf = expf(-(2.0f * (float)d / (float)Dm) * 9.210340371976184f); // ln(10000)
    pe = sinf(ps * invf);
  } else {
    int j = d - Dm / 2;
    float invf = expf(-(2.0f * (float)j / (float)Dm) * 9.210340371976184f);
    pe = cosf(ps * invf);
  }
  float val = e + pe;
  h[idx] = val;
  hb[idx] = f2b(val);
}

// pack one layer's weights to bf16 into wb:
//   [qkv 2304x768 | wo 768x768 | w1 3072x768 | w2 768x3072]  (all B^T, K contiguous)
#define SEG_QKV 1769472
#define SEG_WO  2359296
#define SEG_W1  4718592
#define SEG_END 7077888
__global__ void convw_kernel(const float* __restrict__ Wq, const float* __restrict__ Wkv,
                             const float* __restrict__ Wo, const float* __restrict__ W1,
                             const float* __restrict__ W2, bf16* __restrict__ dst) {
  int idx = (blockIdx.x * blockDim.x + threadIdx.x) * 4;
  if (idx >= SEG_END) return;
  const float* src;
  if (idx < SEG_QKV) {
    src = (idx < 589824) ? Wq + idx : Wkv + (idx - 589824);
  } else if (idx < SEG_WO) {
    src = Wo + (idx - SEG_QKV);
  } else if (idx < SEG_W1) {
    src = W1 + (idx - SEG_WO);
  } else {
    src = W2 + (idx - SEG_W1);
  }
  float4 f = *(const float4*)src;
  bf16 b0 = f2b(f.x), b1 = f2b(f.y), b2 = f2b(f.z), b3 = f2b(f.w);
  unsigned short o[4];
  o[0] = *(unsigned short*)&b0; o[1] = *(unsigned short*)&b1;
  o[2] = *(unsigned short*)&b2; o[3] = *(unsigned short*)&b3;
  *(uint2*)((unsigned short*)dst + idx) = *(uint2*)o;
}

// C[M,N] = A[M,K] @ W[N,K]^T (+bias)(+relu). bf16 in, fp32 acc, OT out.
// 256 thr = 4 waves (2x2). BN=128, BM=32*MREP (128 or 64), BK=32.
// Double-buffered 2-phase K-loop: stage(t+1) issued BEFORE compute(t); one
// barrier per K-step drains vmcnt(0) -> load latency overlaps this block's
// own ds_read+MFMA (critical at low blocks/CU).
// SPLITK>1: blockIdx.z selects K-chunk; fp32 partials at slice stride
// gridDim.y*BM*ldc; bias/relu applied by gemmred_kernel afterwards.
// LDS layout = MFMA-fragment order: 16-row tile T (1KB) holds elem (m,k) at
// T*512 + (k>>3)*128 + (m&15)*8 + (k&7). global_load_lds writes linearly
// (lane*16B), so the per-lane GLOBAL source is pre-swizzled to match.
template <int MREP, int RELU, int SPLITK, typename OT>
__global__ __launch_bounds__(256) void gemm_async(const bf16* __restrict__ A,
                                                  const bf16* __restrict__ W,
                                                  const float* __restrict__ bias,
                                                  OT* __restrict__ C,
                                                  int ldc, int K) {
  constexpr int BM = MREP * 32;
  __shared__ __align__(16) unsigned short Asm[2][BM * 32];
  __shared__ __align__(16) unsigned short Bsm[2][128 * 32];
  const int t = threadIdx.x;
  const int w = t >> 6, lane = t & 63;
  const int col = lane & 15, quad = lane >> 4;
  const int wm = w >> 1, wn = w & 1;
  const int m0 = blockIdx.y * BM, n0 = blockIdx.x * 128;
  const int Kc = K / SPLITK;
  const int kbeg = (SPLITK > 1) ? blockIdx.z * Kc : 0;

  const bf16* aSrc = A + (size_t)(m0 + w * 16 + col) * K + kbeg + quad * 8;
  const bf16* bSrc = W + (size_t)(n0 + w * 16 + col) * K + kbeg + quad * 8;

  const f32x4 zf = {0.0f, 0.0f, 0.0f, 0.0f};
  f32x4 acc[MREP][4];
  #pragma unroll
  for (int mt = 0; mt < MREP; mt++)
    #pragma unroll
    for (int nt = 0; nt < 4; nt++) acc[mt][nt] = zf;

  // prologue: stage tile 0 into buf 0
  #pragma unroll
  for (int i = 0; i < MREP / 2; i++)
    async_cp16(aSrc + (size_t)i * 64 * K, &Asm[0][i * 2048 + w * 512]);
  #pragma unroll
  for (int i = 0; i < 2; i++)
    async_cp16(bSrc + (size_t)i * 64 * K, &Bsm[0][i * 2048 + w * 512]);
  __syncthreads();                 // vmcnt(0) drain before barrier

  int cur = 0;
  for (int kk = 32; kk < Kc; kk += 32) {
    // stage next tile into the other buffer (latency hides under compute)
    #pragma unroll
    for (int i = 0; i < MREP / 2; i++)
      async_cp16(aSrc + kk + (size_t)i * 64 * K, &Asm[cur ^ 1][i * 2048 + w * 512]);
    #pragma unroll
    for (int i = 0; i < 2; i++)
      async_cp16(bSrc + kk + (size_t)i * 64 * K, &Bsm[cur ^ 1][i * 2048 + w * 512]);
    // compute current tile
    bf16x8 af[MREP], bfr[4];
    #pragma unroll
    for (int mt = 0; mt < MREP; mt++)
      af[mt] = *(const bf16x8*)&Asm[cur][(wm * MREP + mt) * 512 + lane * 8];
    #pragma unroll
    for (int nt = 0; nt < 4; nt++)
      bfr[nt] = *(const bf16x8*)&Bsm[cur][(wn * 4 + nt) * 512 + lane * 8];
    #pragma unroll
    for (int mt = 0; mt < MREP; mt++)
      #pragma unroll
      for (int nt = 0; nt < 4; nt++)
        acc[mt][nt] = __builtin_amdgcn_mfma_f32_16x16x32_bf16(af[mt], bfr[nt],
                                                              acc[mt][nt], 0, 0, 0);
    __syncthreads();               // drains next-tile stage; protects buf reuse
    cur ^= 1;
  }
  {
    // final tile
    bf16x8 af[MREP], bfr[4];
    #pragma unroll
    for (int mt = 0; mt < MREP; mt++)
      af[mt] = *(const bf16x8*)&Asm[cur][(wm * MREP + mt) * 512 + lane * 8];
    #pragma unroll
    for (int nt = 0; nt < 4; nt++)
      bfr[nt] = *(const bf16x8*)&Bsm[cur][(wn * 4 + nt) * 512 + lane * 8];
    #pragma unroll
    for (int mt = 0; mt < MREP; mt++)
      #pragma unroll
      for (int nt = 0; nt < 4; nt++)
        acc[mt][nt] = __builtin_amdgcn_mfma_f32_16x16x32_bf16(af[mt], bfr[nt],
                                                              acc[mt][nt], 0, 0, 0);
  }

  OT* Cb = C;
  if (SPLITK > 1)
    Cb = C + (size_t)blockIdx.z * gridDim.y * BM * ldc;
  #pragma unroll
  for (int nt = 0; nt < 4; nt++) {
    const int colg = n0 + wn * 64 + nt * 16 + col;
    const float bv = bias ? bias[colg] : 0.0f;
    #pragma unroll
    for (int mt = 0; mt < MREP; mt++) {
      #pragma unroll
      for (int r = 0; r < 4; r++) {
        const int row = m0 + wm * (MREP * 16) + mt * 16 + quad * 4 + r;
        float val = acc[mt][nt][r] + bv;
        if (RELU) val = fmaxf(val, 0.0f);
        if constexpr (__is_same(OT, float)) {
          Cb[(size_t)row * ldc + colg] = val;
        } else {
          Cb[(size_t)row * ldc + colg] = f2b(val);
        }
      }
    }
  }
}

// out[i] = f2b( sum_z part[z][i] + bias[i % N] )  (optional relu)
template <int NSLICE, int RELU>
__global__ void gemmred_kernel(const float* __restrict__ part, const float* __restrict__ bias,
                               bf16* __restrict__ out, int N, size_t MN) {
  size_t i4 = ((size_t)blockIdx.x * blockDim.x + threadIdx.x) * 4;
  if (i4 >= MN) return;
  float4 a = *(const float4*)(part + i4);
  #pragma unroll
  for (int z = 1; z < NSLICE; z++) {
    float4 p = *(const float4*)(part + (size_t)z * MN + i4);
    a.x += p.x; a.y += p.y; a.z += p.z; a.w += p.w;
  }
  if (bias) {
    int colb = (int)(i4 % N);
    a.x += bias[colb]; a.y += bias[colb + 1]; a.z += bias[colb + 2]; a.w += bias[colb + 3];
  }
  if (RELU) {
    a.x = fmaxf(a.x, 0.0f); a.y = fmaxf(a.y, 0.0f);
    a.z = fmaxf(a.z, 0.0f); a.w = fmaxf(a.w, 0.0f);
  }
  bf16 b0 = f2b(a.x), b1 = f2b(a.y), b2 = f2b(a.z), b3 = f2b(a.w);
  unsigned short o[4];
  o[0] = *(unsigned short*)&b0; o[1] = *(unsigned short*)&b1;
  o[2] = *(unsigned short*)&b2; o[3] = *(unsigned short*)&b3;
  *(uint2*)((unsigned short*)out + i4) = *(uint2*)o;
}

// Flash attention with MFMA. Block = 256 thr = 4 waves; one 64-row Q tile per (b,n).
// q/k/v read from fused qkv buffer (row stride QS); att written with stride Dm.
__global__ __launch_bounds__(256) void attn_flash(const bf16* __restrict__ q,
                                                  const bf16* __restrict__ k,
                                                  const bf16* __restrict__ v,
                                                  bf16* __restrict__ att) {
  const int it = blockIdx.x;       // q-tile index (16)
  const int bn = blockIdx.y;       // b*NH+n (48)
  const int b = bn / NH, n = bn % NH;
  const int t = threadIdx.x;
  const int w = t >> 6, lane = t & 63;
  const int col = lane & 15, quad = lane >> 4;
  const int i0 = it * 64;

  __shared__ __align__(16) unsigned short Kt[64 * 72];  // K[j][d], row stride 72
  __shared__ __align__(16) unsigned short Vt[64 * 72];  // V^T[d][j]
  __shared__ __align__(16) unsigned short Pw[64 * 72];  // per-wave P rows

  const unsigned short* qp = (const unsigned short*)q;
  const unsigned short* kp = (const unsigned short*)k;
  const unsigned short* vp = (const unsigned short*)v;

  bf16x8 aq[2];
  {
    size_t qb = ((size_t)(i0 + w * 16 + col) * B + b) * QS + n * DH + quad * 8;
    aq[0] = *(const bf16x8*)(qp + qb);
    aq[1] = *(const bf16x8*)(qp + qb + 32);
  }

  const f32x4 zf = {0.0f, 0.0f, 0.0f, 0.0f};
  float mrow[4], lrow[4];
  f32x4 o[4];
  #pragma unroll
  for (int r = 0; r < 4; r++) { mrow[r] = -1e30f; lrow[r] = 0.0f; }
  #pragma unroll
  for (int db = 0; db < 4; db++) o[db] = zf;

  const int jj = t >> 2;           // 0..63 (staging row)
  const int d0 = (t & 3) << 4;     // 0,16,32,48

  for (int jt = 0; jt <= it; jt++) {
    const int j0 = jt * 64;
    __syncthreads();
    {
      size_t gb = ((size_t)(j0 + jj) * B + b) * QS + n * DH + d0;
      *(uint4*)&Kt[jj * 72 + d0] = *(const uint4*)(kp + gb);
      *(uint4*)&Kt[jj * 72 + d0 + 8] = *(const uint4*)(kp + gb + 8);
      unsigned short tv[16];
      *(uint4*)tv = *(const uint4*)(vp + gb);
      *(uint4*)(tv + 8) = *(const uint4*)(vp + gb + 8);
      #pragma unroll
      for (int x = 0; x < 16; x++) Vt[(d0 + x) * 72 + jj] = tv[x];
    }
    __syncthreads();

    f32x4 sf[4];
    #pragma unroll
    for (int nb = 0; nb < 4; nb++) sf[nb] = zf;
    #pragma unroll
    for (int ks = 0; ks < 2; ks++) {
      #pragma unroll
      for (int nb = 0; nb < 4; nb++) {
        bf16x8 kb = *(const bf16x8*)&Kt[(nb * 16 + col) * 72 + ks * 32 + quad * 8];
        sf[nb] = __builtin_amdgcn_mfma_f32_16x16x32_bf16(aq[ks], kb, sf[nb], 0, 0, 0);
      }
    }

    const bool diag = (jt == it);
    #pragma unroll
    for (int r = 0; r < 4; r++) {
      const int irow = i0 + w * 16 + quad * 4 + r;
      float sv[4];
      #pragma unroll
      for (int nb = 0; nb < 4; nb++) {
        float s = sf[nb][r] * 0.125f;
        if (diag && (j0 + nb * 16 + col) > irow) s = -1e30f;
        sv[nb] = s;
      }
      float rm = fmaxf(fmaxf(sv[0], sv[1]), fmaxf(sv[2], sv[3]));
      #pragma unroll
      for (int off = 8; off > 0; off >>= 1) rm = fmaxf(rm, __shfl_xor(rm, off, 64));
      const float mn = fmaxf(mrow[r], rm);
      const float alpha = __expf(mrow[r] - mn);
      mrow[r] = mn;
      float ps = 0.0f;
      #pragma unroll
      for (int nb = 0; nb < 4; nb++) {
        float p = __expf(sv[nb] - mn);
        ps += p;
        bf16 hb = f2b(p);
        Pw[(w * 16 + quad * 4 + r) * 72 + nb * 16 + col] = *(unsigned short*)&hb;
      }
      #pragma unroll
      for (int off = 8; off > 0; off >>= 1) ps += __shfl_xor(ps, off, 64);
      lrow[r] = lrow[r] * alpha + ps;
      #pragma unroll
      for (int db = 0; db < 4; db++) o[db][r] *= alpha;
    }

    #pragma unroll
    for (int ks = 0; ks < 2; ks++) {
      bf16x8 pa = *(const bf16x8*)&Pw[(w * 16 + col) * 72 + ks * 32 + quad * 8];
      #pragma unroll
      for (int db = 0; db < 4; db++) {
        bf16x8 vb = *(const bf16x8*)&Vt[(db * 16 + col) * 72 + ks * 32 + quad * 8];
        o[db] = __builtin_amdgcn_mfma_f32_16x16x32_bf16(pa, vb, o[db], 0, 0, 0);
      }
    }
  }

  unsigned short* ap = (unsigned short*)att;
  #pragma unroll
  for (int r = 0; r < 4; r++) {
    const int irow = i0 + w * 16 + quad * 4 + r;
    const float inv = 1.0f / lrow[r];
    size_t ob = ((size_t)irow * B + b) * Dm + n * DH + col;
    #pragma unroll
    for (int db = 0; db < 4; db++) {
      bf16 hb = f2b(o[db][r] * inv);
      ap[ob + db * 16] = *(unsigned short*)&hb;
    }
  }
}

// MFMA meminfer: per (b,n), num[s,v] = cQ[s,:]@mem[:,v], den[s] = cQ[s,:]@mnorm
// (and same with cK for delta). B operand = mem^T in fragment layout, with a 5th
// 16-row tile whose row 0 is mnorm -> dens fall out of the same MFMAs (col 64).
// Grid: 16 s-tiles (64 rows) x 48 bn = 768 blocks, 256 thr = 4 waves.
// Then: att = gate*num/den + (1-gate)*att;  vd = k - numk/denk.
__global__ __launch_bounds__(256) void meminfer_mfma(const bf16* __restrict__ qkv,
                                                     const float* __restrict__ mem,
                                                     const float* __restrict__ mnorm,
                                                     bf16* __restrict__ att,
                                                     bf16* __restrict__ vd) {
  const int s0 = blockIdx.x * 64;
  const int bn = blockIdx.y;
  const int b = bn / NH, n = bn % NH;
  const int t = threadIdx.x;
  const int w = t >> 6, lane = t & 63;
  const int col = lane & 15, quad = lane >> 4;

  // fragment layout addr(row,k) = (row>>4)*1024 + (k>>5)*512 + ((k&31)>>3)*128
  //                              + (row&15)*8 + (k&7)
  __shared__ __align__(16) unsigned short CQ[4096];   // cQ rows 0..63, k 0..63
  __shared__ __align__(16) unsigned short CK[4096];   // cK rows
  __shared__ __align__(16) unsigned short Bm[5120];   // mem^T (4 tiles) + mnorm tile

  const unsigned short* qp = (const unsigned short*)qkv;

  // stage cQ/cK: thread handles row r = t>>2, 16 k at k0 = (t&3)*16
  {
    int r = t >> 2;
    int k0 = (t & 3) * 16;
    size_t gb = ((size_t)(s0 + r) * B + b) * QS + n * DH + k0;
    int abase = (r >> 4) * 1024 + (k0 >> 5) * 512 + ((k0 & 31) >> 3) * 128 + (r & 15) * 8;
    unsigned short tq[16], tv[16], oq[16], ov[16];
    *(uint4*)tq = *(const uint4*)(qp + gb);
    *(uint4*)(tq + 8) = *(const uint4*)(qp + gb + 8);
    *(uint4*)tv = *(const uint4*)(qp + gb + 1536);
    *(uint4*)(tv + 8) = *(const uint4*)(qp + gb + 1536 + 8);
    #pragma unroll
    for (int i = 0; i < 16; i++) {
      float fq = b2f(*(const bf16*)&tq[i]);
      float fv = b2f(*(const bf16*)&tv[i]);
      float eq = fq > 0.0f ? fq + 1.0f : __expf(fq);
      float ev = fv > 0.0f ? fv + 1.0f : __expf(fv);
      bf16 bq = f2b(eq), bv2 = f2b(ev);
      oq[i] = *(unsigned short*)&bq;
      ov[i] = *(unsigned short*)&bv2;
    }
    *(bf16x8*)&CQ[abase] = *(bf16x8*)oq;
    *(bf16x8*)&CQ[abase + 128] = *(bf16x8*)(oq + 8);
    *(bf16x8*)&CK[abase] = *(bf16x8*)ov;
    *(bf16x8*)&CK[abase + 128] = *(bf16x8*)(ov + 8);
  }
  // stage mem^T: thread handles column v = t&63, 16 k at kb = (t>>6)*16
  {
    int v = t & 63, kb = (t >> 6) * 16;
    const float* mp = mem + (size_t)bn * DH * DH;
    #pragma unroll
    for (int i = 0; i < 16; i++) {
      int k = kb + i;
      bf16 mb = f2b(mp[(size_t)k * DH + v]);
      int addr = (v >> 4) * 1024 + (k >> 5) * 512 + ((k & 31) >> 3) * 128 + (v & 15) * 8 + (k & 7);
      Bm[addr] = *(unsigned short*)&mb;
    }
  }
  // stage mnorm tile (tile 4): row 0 = mnorm, rows 1..15 = 0
  {
    int a = t * 4;                       // 4 consecutive shorts within tile 4
    int m = (a >> 3) & 15;
    int kk = (a >> 9) * 32 + ((a >> 7) & 3) * 8 + (a & 7);
    unsigned short vals[4] = {0, 0, 0, 0};
    if (m == 0) {
      const float* np = mnorm + (size_t)bn * DH;
      #pragma unroll
      for (int j = 0; j < 4; j++) {
        bf16 nb = f2b(np[kk + j]);
        vals[j] = *(unsigned short*)&nb;
      }
    }
    *(uint2*)&Bm[4096 + a] = *(uint2*)vals;
  }
  __syncthreads();

  const f32x4 zf = {0.0f, 0.0f, 0.0f, 0.0f};
  f32x4 aq[5], ak[5];
  #pragma unroll
  for (int nb = 0; nb < 5; nb++) { aq[nb] = zf; ak[nb] = zf; }
  #pragma unroll
  for (int ks = 0; ks < 2; ks++) {
    bf16x8 fq = *(const bf16x8*)&CQ[w * 1024 + ks * 512 + lane * 8];
    bf16x8 fk = *(const bf16x8*)&CK[w * 1024 + ks * 512 + lane * 8];
    #pragma unroll
    for (int nb = 0; nb < 5; nb++) {
      bf16x8 bm = *(const bf16x8*)&Bm[nb * 1024 + ks * 512 + lane * 8];
      aq[nb] = __builtin_amdgcn_mfma_f32_16x16x32_bf16(fq, bm, aq[nb], 0, 0, 0);
      ak[nb] = __builtin_amdgcn_mfma_f32_16x16x32_bf16(fk, bm, ak[nb], 0, 0, 0);
    }
  }

  const float gate = 1.0f / (1.0f + expf(-0.01f));
  unsigned short* ap = (unsigned short*)att;
  unsigned short* vp2 = (unsigned short*)vd;
  #pragma unroll
  for (int r = 0; r < 4; r++) {
    const int srow = s0 + w * 16 + quad * 4 + r;
    const float denq = __shfl(aq[4][r], lane & 48, 64);   // col 64 (den) lives at col==0
    const float denk = __shfl(ak[4][r], lane & 48, 64);
    const size_t bd = ((size_t)srow * B + b) * Dm + n * DH + col;
    const size_t bq = ((size_t)srow * B + b) * QS + 768 + n * DH + col;
    #pragma unroll
    for (int nb = 0; nb < 4; nb++) {
      float content = aq[nb][r] / denq;
      float delta = ak[nb][r] / denk;
      float attv = b2f(*(const bf16*)&ap[bd + nb * 16]);
      bf16 ao = f2b(gate * content + (1.0f - gate) * attv);
      ap[bd + nb * 16] = *(unsigned short*)&ao;
      float kvv = b2f(*(const bf16*)&qp[bq + nb * 16]);
      bf16 vo = f2b(kvv - delta);
      vp2[bd + nb * 16] = *(unsigned short*)&vo;
    }
  }
}

// pass 1: part[c][bn][k*64+v] = sum_{s in chunk c} cK[s,k]*vd[s,v]
//         pnorm[c][bn][k]     = sum_{s in chunk c} cK[s,k]
// grid = B*NH*MU_CHUNK blocks; plain coalesced stores, NO atomics.
__global__ void memupd_kernel(const bf16* __restrict__ qkv, const bf16* __restrict__ vd,
                              float* __restrict__ part, float* __restrict__ pnorm) {
  int bn = blockIdx.x % (B * NH);
  int c = blockIdx.x / (B * NH);
  int b = bn / NH, n = bn % NH;
  int t = threadIdx.x;        // 256
  int k = t >> 2;             // 0..63
  int v0 = (t & 3) * 16;      // 0,16,32,48
  __shared__ float ckl[8][DH];
  __shared__ float vdl[8][DH];
  float acc[16];
  #pragma unroll
  for (int j = 0; j < 16; j++) acc[j] = 0.0f;
  float nsum = 0.0f;
  const int sBeg = c * (S / MU_CHUNK), sEnd = sBeg + S / MU_CHUNK;
  for (int s0 = sBeg; s0 < sEnd; s0 += 8) {
    #pragma unroll
    for (int i2 = 0; i2 < 2; i2++) {
      int idx = t + i2 * 256;        // 0..511
      int sp = idx >> 6, dd = idx & 63;
      int gq = ((s0 + sp) * B + b) * QS + 1536 + n * DH + dd;   // v
      int gd = ((s0 + sp) * B + b) * Dm + n * DH + dd;          // vd
      float vv = b2f(qkv[gq]);
      ckl[sp][dd] = vv > 0.0f ? vv + 1.0f : expf(vv);
      vdl[sp][dd] = b2f(vd[gd]);
    }
    __syncthreads();
    #pragma unroll
    for (int sp = 0; sp < 8; sp++) {
      float cc = ckl[sp][k];
      if ((t & 3) == 0) nsum += cc;
      #pragma unroll
      for (int j = 0; j < 16; j++) acc[j] += cc * vdl[sp][v0 + j];
    }
    __syncthreads();
  }
  float* prow = part + (size_t)c * (B * NH * DH * DH) + (size_t)bn * DH * DH;
  #pragma unroll
  for (int j4 = 0; j4 < 4; j4++) {
    float4 o;
    o.x = acc[j4 * 4 + 0]; o.y = acc[j4 * 4 + 1];
    o.z = acc[j4 * 4 + 2]; o.w = acc[j4 * 4 + 3];
    *(float4*)&prow[k * DH + v0 + j4 * 4] = o;
  }
  if ((t & 3) == 0) pnorm[(size_t)c * (B * NH * DH) + bn * DH + k] = nsum;
}

// pass 2: out_mem = mem + sum_c part[c];  out_norm = mnorm + sum_c pnorm[c]
// float4-vectorized; grid covers (786432 + 3072)/4 = 197376 threads = 771 blocks.
__global__ void memred_kernel(const float* __restrict__ mem, const float* __restrict__ mnorm,
                              const float* __restrict__ part, const float* __restrict__ pnorm,
                              float* __restrict__ out_mem, float* __restrict__ out_norm) {
  const int MEMN = B * NH * DH * DH;   // 786432
  int i = blockIdx.x * blockDim.x + threadIdx.x;
  if (i < MEMN / 4) {
    int i4 = i * 4;
    float4 a = *(const float4*)(mem + i4);
    #pragma unroll
    for (int c = 0; c < MU_CHUNK; c++) {
      float4 p = *(const float4*)(part + (size_t)c * MEMN + i4);
      a.x += p.x; a.y += p.y; a.z += p.z; a.w += p.w;
    }
    *(float4*)(out_mem + i4) = a;
  } else {
    int j4 = (i - MEMN / 4) * 4;
    if (j4 < B * NH * DH) {
      float4 a = *(const float4*)(mnorm + j4);
      #pragma unroll
      for (int c = 0; c < MU_CHUNK; c++) {
        float4 p = *(const float4*)(pnorm + (size_t)c * (B * NH * DH) + j4);
        a.x += p.x; a.y += p.y; a.z += p.z; a.w += p.w;
      }
      *(float4*)(out_norm + j4) = a;
    }
  }
}

// out = layer_norm(x + y, g, b); one block per row of 768. fp32 and/or bf16 out.
template <typename TX, typename TY>
__global__ void addln_kernel(const TX* __restrict__ x, const TY* __restrict__ y,
                             const float* __restrict__ g, const float* __restrict__ bb,
                             float* __restrict__ outf, bf16* __restrict__ outb) {
  int row = blockIdx.x;
  int t = threadIdx.x;      // 256
  float vals[3];
  float sum = 0.0f, sq = 0.0f;
  #pragma unroll
  for (int i = 0; i < 3; i++) {
    size_t idx = (size_t)row * Dm + t + i * 256;
    float vv = ldv(x, idx) + ldv(y, idx);
    vals[i] = vv;
    sum += vv;
    sq += vv * vv;
  }
  sum = wave_sum(sum);
  sq = wave_sum(sq);
  __shared__ float s1[4], s2[4];
  int w = t >> 6, lane = t & 63;
  if (lane == 0) { s1[w] = sum; s2[w] = sq; }
  __syncthreads();
  if (t == 0) {
    s1[0] = s1[0] + s1[1] + s1[2] + s1[3];
    s2[0] = s2[0] + s2[1] + s2[2] + s2[3];
  }
  __syncthreads();
  sum = s1[0]; sq = s2[0];
  float mu = sum / 768.0f;
  float var = sq / 768.0f - mu * mu;
  float rs = rsqrtf(var + 1e-5f);
  #pragma unroll
  for (int i = 0; i < 3; i++) {
    int d = t + i * 256;
    float o = (vals[i] - mu) * rs * g[d] + bb[d];
    size_t idx = (size_t)row * Dm + d;
    if (outf) outf[idx] = o;
    if (outb) outb[idx] = f2b(o);
  }
}

extern "C" void kernel_launch(void* const* d_in, const int* in_sizes, int n_in,
                              void* d_out, int out_size, void* d_ws, size_t ws_size,
                              hipStream_t stream) {
  (void)in_sizes; (void)n_in; (void)out_size;
  const int*   inp   = (const int*)d_in[0];
  const float* wemb  = (const float*)d_in[1];
  const float* Wq    = (const float*)d_in[2];
  const float* Wkv   = (const float*)d_in[3];
  const float* Wo    = (const float*)d_in[4];
  const float* ln1g  = (const float*)d_in[5];
  const float* ln1b  = (const float*)d_in[6];
  const float* fW1   = (const float*)d_in[7];
  const float* fb1   = (const float*)d_in[8];
  const float* fW2   = (const float*)d_in[9];
  const float* fb2   = (const float*)d_in[10];
  const float* ln2g  = (const float*)d_in[11];
  const float* ln2b  = (const float*)d_in[12];
  const float* mem   = (const float*)d_in[13];
  const float* mnorm = (const float*)d_in[14];

  const size_t SBD = (size_t)S * B * Dm;   // 3,145,728

  bf16* ws   = (bf16*)d_ws;
  bf16* qkv  = ws;              // slots 0-2: fused qkv, [4096][2304]
  bf16* vd   = ws + 3 * SBD;    // slot 3
  bf16* att  = ws + 4 * SBD;    // slot 4 (aliased: h_bf, ff2o — all disjoint in time)
  bf16* hbf  = att;
  bf16* ff2o = att;
  bf16* out1 = ws + 5 * SBD;    // slot 5
  bf16* wb   = ws + 6 * SBD;    // bf16 weight pack for current layer (7,077,888 elems)
  bf16* ffm  = ws;              // 4*SBD: aliases slots 0-3 (dead by FF1)
  bf16* tmp  = ws;              // Wo-GEMM out (qkv dead after memupd)
  // memupd partials: out1 slot is dead during memupd (written later by addln).
  // 8 chunks x 48 bn x 4096 fp32 = 6,291,456 B = exactly the out1 slot.
  float* part  = (float*)out1;
  float* pnorm = (float*)(wb + SEG_END);   // 8 x 48 x 64 fp32 = 96 KiB past wb
  // split-K partials for Wo/FF2: 2 slices x 4096 x 768 fp32 = 25.2 MB, past pnorm.
  float* partg = pnorm + (size_t)MU_CHUNK * B * NH * DH;
  const size_t need = ((size_t)(6 * SBD + SEG_END)) * 2 +
                      ((size_t)MU_CHUNK * B * NH * DH + 2 * SBD) * 4;
  const bool use_splitk = (ws_size >= need);

  float* h    = (float*)d_out;  // residual stream lives in d_out (fp32)
  float* outm = h + SBD;
  float* outn = outm + (size_t)NL * B * NH * DH * DH;

  dim3 b256(256);
  embed_kernel<<<dim3((S * B * Dm + 255) / 256), b256, 0, stream>>>(inp, wemb, h, hbf);

  for (int l = 0; l < NL; l++) {
    convw_kernel<<<dim3(SEG_END / 4 / 256), b256, 0, stream>>>(
        Wq + (size_t)l * Dm * Dm, Wkv + (size_t)l * 2 * Dm * Dm,
        Wo + (size_t)l * Dm * Dm, fW1 + (size_t)l * DI * Dm,
        fW2 + (size_t)l * Dm * DI, wb);
    const bf16* wqkv = wb;
    const bf16* wo_b = wb + SEG_QKV;
    const bf16* w1_b = wb + SEG_WO;
    const bf16* w2_b = wb + SEG_W1;
    const float* mem_l = mem + (size_t)l * B * NH * DH * DH;
    const float* mn_l  = mnorm + (size_t)l * B * NH * DH;
    float* outm_l = outm + (size_t)l * B * NH * DH * DH;
    float* outn_l = outn + (size_t)l * B * NH * DH;

    // fused QKV: M=4096, N=2304, K=768 -> 576 blocks
    gemm_async<4, 0, 1, bf16><<<dim3(QS / 128, 32), b256, 0, stream>>>(
        hbf, wqkv, nullptr, qkv, QS, Dm);

    attn_flash<<<dim3(S / 64, B * NH), b256, 0, stream>>>(qkv, qkv + 768, qkv + 1536, att);
    meminfer_mfma<<<dim3(S / 64, B * NH), b256, 0, stream>>>(qkv, mem_l, mn_l, att, vd);
    memupd_kernel<<<dim3(B * NH * MU_CHUNK), b256, 0, stream>>>(qkv, vd, part, pnorm);
    memred_kernel<<<dim3(771), b256, 0, stream>>>(mem_l, mn_l, part, pnorm, outm_l, outn_l);

    // Wo: M=4096, N=768, K=768
    if (use_splitk) {
      gemm_async<2, 0, 2, float><<<dim3(Dm / 128, 64, 2), b256, 0, stream>>>(
          att, wo_b, nullptr, partg, Dm, Dm);
      gemmred_kernel<2, 0><<<dim3((unsigned)(SBD / 4 / 256)), b256, 0, stream>>>(
          partg, nullptr, tmp, Dm, SBD);
    } else {
      gemm_async<2, 0, 1, bf16><<<dim3(Dm / 128, 64), b256, 0, stream>>>(
          att, wo_b, nullptr, tmp, Dm, Dm);
    }
    addln_kernel<float, bf16><<<dim3(S * B), b256, 0, stream>>>(
        h, tmp, ln1g + l * Dm, ln1b + l * Dm, nullptr, out1);

    // FF1: M=4096, N=3072, K=768 -> 768 blocks
    gemm_async<4, 1, 1, bf16><<<dim3(DI / 128, 32), b256, 0, stream>>>(
        out1, w1_b, fb1 + (size_t)l * DI, ffm, DI, Dm);
    // FF2: M=4096, N=768, K=3072
    if (use_splitk) {
      gemm_async<2, 0, 2, float><<<dim3(Dm / 128, 64, 2), b256, 0, stream>>>(
          ffm, w2_b, nullptr, partg, Dm, DI);
      gemmred_kernel<2, 0><<<dim3((unsigned)(SBD / 4 / 256)), b256, 0, stream>>>(
          partg, fb2 + (size_t)l * Dm, ff2o, Dm, SBD);
    } else {
      gemm_async<2, 0, 1, bf16><<<dim3(Dm / 128, 64), b256, 0, stream>>>(
          ffm, w2_b, fb2 + (size_t)l * Dm, ff2o, Dm, DI);
    }
    addln_kernel<bf16, bf16><<<dim3(S * B), b256, 0, stream>>>(
        out1, ff2o, ln2g + l * Dm, ln2b + l * Dm, h, hbf);
  }
}